// Round 1
// baseline (532.745 us; speedup 1.0000x reference)
//
#include <hip/hip_runtime.h>

#define EPS 1e-5f

// problem sizes
#define B    512
#define C_IN 12
#define L_IN 5000
#define C1   32
#define KK1  50
#define L1   496   // (5000-50)/10+1
#define NF   32
#define KK2  25
#define L2   95    // (496-25)/5+1
#define LAT  32
#define HID  64
#define T    L2

// ---------------- weight transpose: w[o][ck] -> wT[ck][o] ----------------
__global__ void k_transpose_w(const float* __restrict__ c1w, const float* __restrict__ c2w,
                              float* __restrict__ wT1, float* __restrict__ wT2) {
    int i = blockIdx.x * 256 + threadIdx.x;
    if (i < 19200) {                 // 12*50*32
        int ck = i >> 5, o = i & 31;
        wT1[i] = c1w[o * 600 + ck];
    } else if (i < 19200 + 25600) {  // 32*25*32
        int j = i - 19200;
        int ck = j >> 5, o = j & 31;
        wT2[j] = c2w[o * 800 + ck];
    }
}

// ---------------- conv1 + bias + BN1 stats ----------------
// grid (2, B), 256 thr. thread = one output t, all 32 channels in regs.
__global__ __launch_bounds__(256) void k_conv1(const float* __restrict__ x,
                                               const float* __restrict__ wT1,
                                               const float* __restrict__ c1b,
                                               float* __restrict__ y1,
                                               float* __restrict__ stats1) {
    __shared__ float xs[2600];
    __shared__ float redS[128], redQ[128];
    const int chunk = blockIdx.x;
    const int b = blockIdx.y;
    const int tid = threadIdx.x;
    const int t0 = chunk * 256;
    const int nt = (chunk == 0) ? 256 : (L1 - 256); // 256 / 240
    const int nload = nt * 10 + 40;
    const float* xb = x + (size_t)b * (C_IN * L_IN) + t0 * 10;
    const bool active = tid < nt;

    float acc[C1];
#pragma unroll
    for (int o = 0; o < C1; ++o) acc[o] = 0.f;

    for (int c = 0; c < C_IN; ++c) {
        __syncthreads();
        for (int i = tid; i < nload; i += 256) xs[i] = xb[c * L_IN + i];
        __syncthreads();
        if (active) {
            const float* wc = wT1 + c * 50 * 32;
            for (int kk = 0; kk < 25; ++kk) {
                const float2 xv = *reinterpret_cast<const float2*>(&xs[10 * tid + 2 * kk]);
                const float* w0 = wc + (2 * kk) * 32;  // uniform -> scalar loads
#pragma unroll
                for (int o = 0; o < C1; ++o) acc[o] = fmaf(xv.x, w0[o], acc[o]);
#pragma unroll
                for (int o = 0; o < C1; ++o) acc[o] = fmaf(xv.y, w0[32 + o], acc[o]);
            }
        }
    }
    float val[C1];
#pragma unroll
    for (int o = 0; o < C1; ++o) val[o] = active ? (acc[o] + c1b[o]) : 0.f;
    if (active) {
        float* yrow = y1 + (size_t)b * (C1 * L1) + t0 + tid;
#pragma unroll
        for (int o = 0; o < C1; ++o) yrow[o * L1] = val[o];
    }
    // block reduce (sum, sumsq) per channel -> atomics
    const int lane = tid & 63, wave = tid >> 6;
    for (int o = 0; o < C1; ++o) {
        float s = val[o], q = val[o] * val[o];
#pragma unroll
        for (int off = 32; off >= 1; off >>= 1) { s += __shfl_xor(s, off); q += __shfl_xor(q, off); }
        if (lane == 0) { redS[wave * 32 + o] = s; redQ[wave * 32 + o] = q; }
    }
    __syncthreads();
    if (tid < 64) {
        int o = tid & 31;
        if (tid < 32) atomicAdd(&stats1[o],      redS[o] + redS[32 + o] + redS[64 + o] + redS[96 + o]);
        else          atomicAdd(&stats1[32 + o], redQ[o] + redQ[32 + o] + redQ[64 + o] + redQ[96 + o]);
    }
}

// ---------------- BN finalize: (sum,sumsq) -> (scale, shift) ----------------
__global__ void k_bnfin(float* __restrict__ stats, const float* __restrict__ g,
                        const float* __restrict__ bb, float count) {
    int o = threadIdx.x;
    if (o < 32) {
        float mean = stats[o] / count;
        float var = stats[32 + o] / count - mean * mean;
        float sc = g[o] * rsqrtf(var + EPS);
        stats[64 + o] = sc;
        stats[96 + o] = bb[o] - mean * sc;
    }
}

// ---------------- conv2 (+BN1+relu on input) + bias + BN2 stats ----------------
// grid B, 128 thr. thread = one output t (95 active), all 32 out channels.
// writes y2 in [T][B][F] layout.
__global__ __launch_bounds__(128) void k_conv2(const float* __restrict__ y1,
                                               const float* __restrict__ wT2,
                                               const float* __restrict__ c2b,
                                               const float* __restrict__ stats1,
                                               float* __restrict__ y2,
                                               float* __restrict__ stats2) {
    __shared__ float xs[L1];
    __shared__ float redS[64], redQ[64];
    const int b = blockIdx.x;
    const int tid = threadIdx.x;
    const bool active = tid < L2;

    float acc[NF];
#pragma unroll
    for (int o = 0; o < NF; ++o) acc[o] = 0.f;

    for (int c = 0; c < C1; ++c) {
        __syncthreads();
        const float sc = stats1[64 + c], sh = stats1[96 + c];
        for (int i = tid; i < L1; i += 128)
            xs[i] = fmaxf(fmaf(y1[(size_t)b * (C1 * L1) + c * L1 + i], sc, sh), 0.f);
        __syncthreads();
        if (active) {
            const float* wc = wT2 + c * 25 * 32;
            for (int k = 0; k < KK2; ++k) {
                const float xv = xs[5 * tid + k];
                const float* w0 = wc + k * 32;
#pragma unroll
                for (int o = 0; o < NF; ++o) acc[o] = fmaf(xv, w0[o], acc[o]);
            }
        }
    }
    float val[NF];
#pragma unroll
    for (int o = 0; o < NF; ++o) val[o] = active ? (acc[o] + c2b[o]) : 0.f;
    if (active) {
        float4* dst = reinterpret_cast<float4*>(y2 + (size_t)tid * (B * NF) + b * NF);
#pragma unroll
        for (int o4 = 0; o4 < 8; ++o4)
            dst[o4] = make_float4(val[4*o4], val[4*o4+1], val[4*o4+2], val[4*o4+3]);
    }
    const int lane = tid & 63, wave = tid >> 6;
    for (int o = 0; o < NF; ++o) {
        float s = val[o], q = val[o] * val[o];
#pragma unroll
        for (int off = 32; off >= 1; off >>= 1) { s += __shfl_xor(s, off); q += __shfl_xor(q, off); }
        if (lane == 0) { redS[wave * 32 + o] = s; redQ[wave * 32 + o] = q; }
    }
    __syncthreads();
    if (tid < 64) {
        int o = tid & 31;
        if (tid < 32) atomicAdd(&stats2[o],      redS[o] + redS[32 + o]);
        else          atomicAdd(&stats2[32 + o], redQ[o] + redQ[32 + o]);
    }
}

// ---------------- BN2+relu, input proj, LN1 -> xt_all [T][B][LAT] ----------------
__global__ __launch_bounds__(256) void k_proj(const float* __restrict__ y2,
                                              const float* __restrict__ stats2,
                                              const float* __restrict__ Wi,
                                              const float* __restrict__ bi,
                                              const float* __restrict__ ln1g,
                                              const float* __restrict__ ln1b,
                                              float* __restrict__ xt_all) {
    const int r = blockIdx.x * 256 + threadIdx.x;
    if (r >= T * B) return;
    const float4* row = reinterpret_cast<const float4*>(y2 + (size_t)r * NF);
    float u[NF];
#pragma unroll
    for (int f4 = 0; f4 < 8; ++f4) {
        float4 v = row[f4];
        u[4*f4]   = fmaxf(fmaf(v.x, stats2[64 + 4*f4],   stats2[96 + 4*f4]),   0.f);
        u[4*f4+1] = fmaxf(fmaf(v.y, stats2[64 + 4*f4+1], stats2[96 + 4*f4+1]), 0.f);
        u[4*f4+2] = fmaxf(fmaf(v.z, stats2[64 + 4*f4+2], stats2[96 + 4*f4+2]), 0.f);
        u[4*f4+3] = fmaxf(fmaf(v.w, stats2[64 + 4*f4+3], stats2[96 + 4*f4+3]), 0.f);
    }
    float v[LAT];
    float s = 0.f, q = 0.f;
#pragma unroll
    for (int l = 0; l < LAT; ++l) {
        float a = bi[l];
#pragma unroll
        for (int f = 0; f < NF; ++f) a = fmaf(u[f], Wi[l * NF + f], a);
        v[l] = a; s += a; q += a * a;
    }
    const float m = s * (1.f / LAT);
    const float inv = rsqrtf(q * (1.f / LAT) - m * m + EPS);
    float4* dst = reinterpret_cast<float4*>(xt_all + (size_t)r * LAT);
#pragma unroll
    for (int l4 = 0; l4 < 8; ++l4) {
        float4 o;
        o.x = (v[4*l4]   - m) * inv * ln1g[4*l4]   + ln1b[4*l4];
        o.y = (v[4*l4+1] - m) * inv * ln1g[4*l4+1] + ln1b[4*l4+1];
        o.z = (v[4*l4+2] - m) * inv * ln1g[4*l4+2] + ln1b[4*l4+2];
        o.w = (v[4*l4+3] - m) * inv * ln1g[4*l4+3] + ln1b[4*l4+3];
        dst[l4] = o;
    }
}

// ---------------- RNN scan + pooled mean + final linear ----------------
// one wave per batch row; lane j owns hp[j]; lanes 0..31 own h[l].
__global__ __launch_bounds__(256) void k_rnn(const float* __restrict__ xt_all,
                                             const float* __restrict__ Wh,
                                             const float* __restrict__ bh,
                                             const float* __restrict__ ln2g,
                                             const float* __restrict__ ln2b,
                                             const float* __restrict__ Wr,
                                             const float* __restrict__ br,
                                             const float* __restrict__ Wo,
                                             const float* __restrict__ bo,
                                             float* __restrict__ out) {
    __shared__ float lds[4 * 96];
    const int tid = threadIdx.x;
    const int wave = tid >> 6, lane = tid & 63;
    const int b = blockIdx.x * 4 + wave;
    const int l = lane & 31;
    float* combS = lds + wave * 96;
    float* hpnS  = lds + wave * 96 + 32;

    float whv[LAT];
#pragma unroll
    for (int i = 0; i < LAT; ++i) whv[i] = Wh[lane * LAT + i];
    const float bh_j = bh[lane];
    const float g_j = ln2g[lane], bb_j = ln2b[lane];
    float wrv[HID];
#pragma unroll
    for (int i = 0; i < HID; ++i) wrv[i] = Wr[l * HID + i];
    const float br_l = br[l];

    float h = 0.f, pooled = 0.f;
    for (int t = 0; t < T; ++t) {
        if (lane < 32) combS[lane] = h + xt_all[(size_t)t * (B * LAT) + b * LAT + lane];
        __syncthreads();
        float a = bh_j;
#pragma unroll
        for (int i = 0; i < 8; ++i) {
            float4 cv = reinterpret_cast<const float4*>(combS)[i];
            a = fmaf(cv.x, whv[4*i], a);   a = fmaf(cv.y, whv[4*i+1], a);
            a = fmaf(cv.z, whv[4*i+2], a); a = fmaf(cv.w, whv[4*i+3], a);
        }
        a = fmaxf(a, 0.f);
        float s = a, q = a * a;
#pragma unroll
        for (int off = 32; off >= 1; off >>= 1) { s += __shfl_xor(s, off); q += __shfl_xor(q, off); }
        const float m = s * (1.f / HID);
        const float inv = rsqrtf(q * (1.f / HID) - m * m + EPS);
        hpnS[lane] = (a - m) * inv * g_j + bb_j;
        __syncthreads();
        float a2 = br_l;
#pragma unroll
        for (int i = 0; i < 16; ++i) {
            float4 hv = reinterpret_cast<const float4*>(hpnS)[i];
            a2 = fmaf(hv.x, wrv[4*i], a2);   a2 = fmaf(hv.y, wrv[4*i+1], a2);
            a2 = fmaf(hv.z, wrv[4*i+2], a2); a2 = fmaf(hv.w, wrv[4*i+3], a2);
        }
        h = tanhf(a2);
        pooled += h;
    }
    pooled *= (1.f / T);
    __syncthreads();
    if (lane < 32) combS[lane] = pooled;
    __syncthreads();
    float wov[LAT];
#pragma unroll
    for (int i = 0; i < LAT; ++i) wov[i] = Wo[l * LAT + i];
    float a3 = bo[l];
#pragma unroll
    for (int i = 0; i < 8; ++i) {
        float4 pv = reinterpret_cast<const float4*>(combS)[i];
        a3 = fmaf(pv.x, wov[4*i], a3);   a3 = fmaf(pv.y, wov[4*i+1], a3);
        a3 = fmaf(pv.z, wov[4*i+2], a3); a3 = fmaf(pv.w, wov[4*i+3], a3);
    }
    if (lane < 32) out[(size_t)b * LAT + l] = a3;
}

extern "C" void kernel_launch(void* const* d_in, const int* in_sizes, int n_in,
                              void* d_out, int out_size, void* d_ws, size_t ws_size,
                              hipStream_t stream) {
    const float* x    = (const float*)d_in[0];
    const float* c1w  = (const float*)d_in[1];
    const float* c1b  = (const float*)d_in[2];
    const float* bn1g = (const float*)d_in[3];
    const float* bn1b = (const float*)d_in[4];
    const float* c2w  = (const float*)d_in[5];
    const float* c2b  = (const float*)d_in[6];
    const float* bn2g = (const float*)d_in[7];
    const float* bn2b = (const float*)d_in[8];
    const float* Wi   = (const float*)d_in[9];
    const float* bi   = (const float*)d_in[10];
    const float* ln1g = (const float*)d_in[11];
    const float* ln1b = (const float*)d_in[12];
    const float* Wh   = (const float*)d_in[13];
    const float* bh   = (const float*)d_in[14];
    const float* ln2g = (const float*)d_in[15];
    const float* ln2b = (const float*)d_in[16];
    const float* Wr   = (const float*)d_in[17];
    const float* br   = (const float*)d_in[18];
    const float* Wo   = (const float*)d_in[19];
    const float* bo   = (const float*)d_in[20];

    float* ws = (float*)d_ws;
    float* stats1 = ws;                 // 128 floats (sum/sumsq/scale/shift)
    float* stats2 = ws + 128;           // 128
    float* wT1 = ws + 256;              // 19200
    float* wT2 = ws + 19456;            // 25600
    float* y1  = ws + 45056;            // 512*32*496 = 8126464
    float* y2  = ws + 45056 + 8126464;  // [T][B][NF] = 1556480
    float* xt  = y2 + 1556480;          // [T][B][LAT] = 1556480
    float* out = (float*)d_out;

    hipMemsetAsync(stats1, 0, 256 * sizeof(float), stream);
    k_transpose_w<<<176, 256, 0, stream>>>(c1w, c2w, wT1, wT2);
    k_conv1<<<dim3(2, B), 256, 0, stream>>>(x, wT1, c1b, y1, stats1);
    k_bnfin<<<1, 32, 0, stream>>>(stats1, bn1g, bn1b, (float)(B * L1));
    k_conv2<<<B, 128, 0, stream>>>(y1, wT2, c2b, stats1, y2, stats2);
    k_bnfin<<<1, 32, 0, stream>>>(stats2, bn2g, bn2b, (float)(B * L2));
    k_proj<<<(T * B + 255) / 256, 256, 0, stream>>>(y2, stats2, Wi, bi, ln1g, ln1b, xt);
    k_rnn<<<B / 4, 256, 0, stream>>>(xt, Wh, bh, ln2g, ln2b, Wr, br, Wo, bo, out);
}

// Round 2
// 415.089 us; speedup vs baseline: 1.2834x; 1.2834x over previous
//
#include <hip/hip_runtime.h>

#define EPS 1e-5f

#define B    512
#define C_IN 12
#define L_IN 5000
#define C1   32
#define L1   496   // (5000-50)/10+1
#define NF   32
#define L2   95    // (496-25)/5+1
#define LAT  32
#define HID  64
#define T    L2

// ---------------- weight transpose: w[o][ck] -> wT[ck][o] ----------------
__global__ void k_transpose_w(const float* __restrict__ c1w, const float* __restrict__ c2w,
                              float* __restrict__ wT1, float* __restrict__ wT2) {
    int i = blockIdx.x * 256 + threadIdx.x;
    if (i < 19200) {                 // 12*50*32
        int ck = i >> 5, o = i & 31;
        wT1[i] = c1w[o * 600 + ck];
    } else if (i < 44800) {          // 32*25*32
        int j = i - 19200;
        int ck = j >> 5, o = j & 31;
        wT2[j] = c2w[o * 800 + ck];
    }
}

// ---------------- conv1 + bias + BN1 stats ----------------
// grid (4, B), 256 thr. One staging phase (12ch x 1280 floats), then thread=(t, oc-half).
__global__ __launch_bounds__(256) void k_conv1(const float* __restrict__ x,
                                               const float* __restrict__ wT1,
                                               const float* __restrict__ c1b,
                                               float* __restrict__ y1,
                                               float* __restrict__ raw1) {
    __shared__ float xs[C_IN][1280];
    __shared__ float redS[4][16], redQ[4][16];
    const int chunk = blockIdx.x, b = blockIdx.y, tid = threadIdx.x;
    const int t0 = chunk * 124;

    // stage: 12 channels x 320 float4 (coalesced)
    const float4* xb = reinterpret_cast<const float4*>(x + (size_t)b * (C_IN * L_IN) + t0 * 10);
    float4* xs4 = reinterpret_cast<float4*>(&xs[0][0]);
    for (int v = tid; v < C_IN * 320; v += 256) {
        int c = v / 320, j = v - c * 320;
        xs4[v] = xb[c * 1250 + j];
    }
    __syncthreads();

    const int half = tid >> 7, tl = tid & 127;
    const int halfu = __builtin_amdgcn_readfirstlane(half);
    const bool active = tl < 124;
    const int xoff = active ? 10 * tl : 0;

    float acc[16];
#pragma unroll
    for (int o = 0; o < 16; ++o) acc[o] = 0.f;

    for (int c = 0; c < C_IN; ++c) {
        const float* wc = wT1 + c * 1600 + halfu * 16;  // uniform -> s_load
#pragma unroll 5
        for (int kk = 0; kk < 25; ++kk) {
            const float2 xv = *reinterpret_cast<const float2*>(&xs[c][xoff + 2 * kk]);
            const float* w0 = wc + kk * 64;
#pragma unroll
            for (int o = 0; o < 16; ++o) acc[o] = fmaf(xv.x, w0[o], acc[o]);
#pragma unroll
            for (int o = 0; o < 16; ++o) acc[o] = fmaf(xv.y, w0[32 + o], acc[o]);
        }
    }
    float val[16];
#pragma unroll
    for (int o = 0; o < 16; ++o) val[o] = active ? (acc[o] + c1b[halfu * 16 + o]) : 0.f;
    if (active) {
        float* yrow = y1 + ((size_t)b * C1 + halfu * 16) * L1 + t0 + tl;
#pragma unroll
        for (int o = 0; o < 16; ++o) yrow[o * L1] = val[o];
    }
    // stats reduce: per-wave shfl, then combine wave pairs, 64 atomics/block (cache-line spread)
    const int lane = tid & 63, wave = tid >> 6;
    for (int o = 0; o < 16; ++o) {
        float s = val[o], q = val[o] * val[o];
#pragma unroll
        for (int off = 32; off >= 1; off >>= 1) { s += __shfl_xor(s, off); q += __shfl_xor(q, off); }
        if (lane == 0) { redS[wave][o] = s; redQ[wave][o] = q; }
    }
    __syncthreads();
    if (tid < 64) {
        int o = tid & 15, grp = (tid >> 4) & 1, isQ = tid >> 5;
        int oc = grp * 16 + o;
        float v = isQ ? (redQ[grp * 2][o] + redQ[grp * 2 + 1][o])
                      : (redS[grp * 2][o] + redS[grp * 2 + 1][o]);
        atomicAdd(&raw1[(isQ ? 1024 : 0) + oc * 16], v);
    }
}

// ---------------- BN finalize: strided raw (sum,sumsq) -> compact (scale, shift) ----------------
__global__ void k_bnfin(const float* __restrict__ raw, const float* __restrict__ g,
                        const float* __restrict__ bb, float* __restrict__ fin, float count) {
    int o = threadIdx.x;
    if (o < 32) {
        float mean = raw[o * 16] / count;
        float var = raw[1024 + o * 16] / count - mean * mean;
        float sc = g[o] * rsqrtf(var + EPS);
        fin[o] = sc;
        fin[32 + o] = bb[o] - mean * sc;
    }
}

// ---------------- conv2 (+BN1+relu on input) + bias + BN2 stats ----------------
// grid B, 256 thr. Stage ALL of y1[b] (63.5KB) once, then thread=(t, oc-half).
// writes y2 in [b][t][f] layout (each lane writes one full 64B line).
__global__ __launch_bounds__(256) void k_conv2(const float* __restrict__ y1,
                                               const float* __restrict__ wT2,
                                               const float* __restrict__ c2b,
                                               const float* __restrict__ fin1,
                                               float* __restrict__ y2,
                                               float* __restrict__ raw2) {
    __shared__ float xs[C1 * L1];  // 32*496 floats
    __shared__ float redS[4][16], redQ[4][16];
    const int b = blockIdx.x, tid = threadIdx.x;

    const float4* src = reinterpret_cast<const float4*>(y1 + (size_t)b * C1 * L1);
    float4* xs4 = reinterpret_cast<float4*>(xs);
    for (int v = tid; v < C1 * 124; v += 256) {
        int c = v / 124;
        float sc = fin1[c], sh = fin1[32 + c];
        float4 d = src[v];
        d.x = fmaxf(fmaf(d.x, sc, sh), 0.f);
        d.y = fmaxf(fmaf(d.y, sc, sh), 0.f);
        d.z = fmaxf(fmaf(d.z, sc, sh), 0.f);
        d.w = fmaxf(fmaf(d.w, sc, sh), 0.f);
        xs4[v] = d;
    }
    __syncthreads();

    const int half = tid >> 7, tl = tid & 127;
    const int halfu = __builtin_amdgcn_readfirstlane(half);
    const bool active = tl < L2;
    const int xoff = active ? 5 * tl : 0;

    float acc[16];
#pragma unroll
    for (int o = 0; o < 16; ++o) acc[o] = 0.f;

    for (int c = 0; c < C1; ++c) {
        const float* xc = xs + c * L1 + xoff;
        const float* wc = wT2 + c * 800 + halfu * 16;  // uniform -> s_load
#pragma unroll 5
        for (int k = 0; k < 25; ++k) {
            const float xv = xc[k];
            const float* w0 = wc + k * 32;
#pragma unroll
            for (int o = 0; o < 16; ++o) acc[o] = fmaf(xv, w0[o], acc[o]);
        }
    }
    float val[16];
#pragma unroll
    for (int o = 0; o < 16; ++o) val[o] = active ? (acc[o] + c2b[halfu * 16 + o]) : 0.f;
    if (active) {
        float4* dst = reinterpret_cast<float4*>(y2 + ((size_t)b * L2 + tl) * NF + halfu * 16);
#pragma unroll
        for (int o4 = 0; o4 < 4; ++o4)
            dst[o4] = make_float4(val[4 * o4], val[4 * o4 + 1], val[4 * o4 + 2], val[4 * o4 + 3]);
    }
    const int lane = tid & 63, wave = tid >> 6;
    for (int o = 0; o < 16; ++o) {
        float s = val[o], q = val[o] * val[o];
#pragma unroll
        for (int off = 32; off >= 1; off >>= 1) { s += __shfl_xor(s, off); q += __shfl_xor(q, off); }
        if (lane == 0) { redS[wave][o] = s; redQ[wave][o] = q; }
    }
    __syncthreads();
    if (tid < 64) {
        int o = tid & 15, grp = (tid >> 4) & 1, isQ = tid >> 5;
        int oc = grp * 16 + o;
        float v = isQ ? (redQ[grp * 2][o] + redQ[grp * 2 + 1][o])
                      : (redS[grp * 2][o] + redS[grp * 2 + 1][o]);
        atomicAdd(&raw2[(isQ ? 1024 : 0) + oc * 16], v);
    }
}

// ---------------- BN2+relu, input proj, LN1, then fold Wh: xt2 = LN1(..)@Wh.T + bh ----------------
// xt2 layout [T][B][HID]
__global__ __launch_bounds__(256) void k_proj(const float* __restrict__ y2,
                                              const float* __restrict__ fin2,
                                              const float* __restrict__ Wi,
                                              const float* __restrict__ bi,
                                              const float* __restrict__ ln1g,
                                              const float* __restrict__ ln1b,
                                              const float* __restrict__ Wh,
                                              const float* __restrict__ bh,
                                              float* __restrict__ xt2) {
    const int r = blockIdx.x * 256 + threadIdx.x;
    if (r >= B * T) return;
    const int b = r / 95, t = r - b * 95;

    const float4* row = reinterpret_cast<const float4*>(y2 + (size_t)r * NF);
    float u[NF];
#pragma unroll
    for (int f4 = 0; f4 < 8; ++f4) {
        float4 v = row[f4];
        u[4*f4]   = fmaxf(fmaf(v.x, fin2[4*f4],   fin2[32 + 4*f4]),   0.f);
        u[4*f4+1] = fmaxf(fmaf(v.y, fin2[4*f4+1], fin2[32 + 4*f4+1]), 0.f);
        u[4*f4+2] = fmaxf(fmaf(v.z, fin2[4*f4+2], fin2[32 + 4*f4+2]), 0.f);
        u[4*f4+3] = fmaxf(fmaf(v.w, fin2[4*f4+3], fin2[32 + 4*f4+3]), 0.f);
    }
    float xln[LAT];
    float s = 0.f, q = 0.f;
#pragma unroll
    for (int l = 0; l < LAT; ++l) {
        float a = bi[l];
#pragma unroll
        for (int f = 0; f < NF; ++f) a = fmaf(u[f], Wi[l * NF + f], a);
        xln[l] = a; s += a; q += a * a;
    }
    const float m = s * (1.f / LAT);
    const float inv = rsqrtf(q * (1.f / LAT) - m * m + EPS);
#pragma unroll
    for (int l = 0; l < LAT; ++l) xln[l] = (xln[l] - m) * inv * ln1g[l] + ln1b[l];

    float4* dst = reinterpret_cast<float4*>(xt2 + ((size_t)t * B + b) * HID);
#pragma unroll
    for (int j4 = 0; j4 < 16; ++j4) {
        float4 o4;
        float a0 = bh[4*j4], a1 = bh[4*j4+1], a2 = bh[4*j4+2], a3 = bh[4*j4+3];
#pragma unroll
        for (int l = 0; l < LAT; ++l) {
            float xl = xln[l];
            a0 = fmaf(xl, Wh[(4*j4)   * LAT + l], a0);
            a1 = fmaf(xl, Wh[(4*j4+1) * LAT + l], a1);
            a2 = fmaf(xl, Wh[(4*j4+2) * LAT + l], a2);
            a3 = fmaf(xl, Wh[(4*j4+3) * LAT + l], a3);
        }
        o4.x = a0; o4.y = a1; o4.z = a2; o4.w = a3;
        dst[j4] = o4;
    }
}

// ---------------- RNN scan + pooled mean + final linear ----------------
// single-wave blocks (64 thr): no s_barrier, LDS ordering via lgkmcnt waits.
__global__ __launch_bounds__(64) void k_rnn(const float* __restrict__ xt2,
                                            const float* __restrict__ Wh,
                                            const float* __restrict__ ln2g,
                                            const float* __restrict__ ln2b,
                                            const float* __restrict__ Wr,
                                            const float* __restrict__ br,
                                            const float* __restrict__ Wo,
                                            const float* __restrict__ bo,
                                            float* __restrict__ out) {
    __shared__ __align__(16) float lds[96];  // [0..63] hp, [64..95] h
    const int lane = threadIdx.x;
    const int b = blockIdx.x;
    const int l = lane & 31;

    float whv[LAT];
#pragma unroll
    for (int i = 0; i < LAT; ++i) whv[i] = Wh[lane * LAT + i];
    float wrv[HID];
#pragma unroll
    for (int i = 0; i < HID; ++i) wrv[i] = Wr[l * HID + i];
    const float g_j = ln2g[lane], bb_j = ln2b[lane];
    const float br_l = br[l];

    float hfull[LAT];
#pragma unroll
    for (int i = 0; i < LAT; ++i) hfull[i] = 0.f;
    float pooled = 0.f;
    float xq = xt2[(size_t)b * HID + lane];  // t=0 (xt2 already = Wh@xt + bh)

    for (int t = 0; t < T; ++t) {
        float xq_next = 0.f;
        if (t + 1 < T) xq_next = xt2[((size_t)(t + 1) * B + b) * HID + lane];

        float a = xq;
#pragma unroll
        for (int i = 0; i < LAT; ++i) a = fmaf(hfull[i], whv[i], a);
        a = fmaxf(a, 0.f);
        float s = a, q = a * a;
#pragma unroll
        for (int off = 32; off >= 1; off >>= 1) { s += __shfl_xor(s, off); q += __shfl_xor(q, off); }
        const float m = s * (1.f / HID);
        const float inv = __builtin_amdgcn_rsqf(q * (1.f / HID) - m * m + EPS);
        const float hpv = (a - m) * inv * g_j + bb_j;

        lds[lane] = hpv;
        asm volatile("s_waitcnt lgkmcnt(0)" ::: "memory");
        float a2 = br_l;
#pragma unroll
        for (int i = 0; i < 16; ++i) {
            float4 hv = reinterpret_cast<const float4*>(lds)[i];
            a2 = fmaf(hv.x, wrv[4*i], a2);   a2 = fmaf(hv.y, wrv[4*i+1], a2);
            a2 = fmaf(hv.z, wrv[4*i+2], a2); a2 = fmaf(hv.w, wrv[4*i+3], a2);
        }
        // tanh via native exp2/rcp: tanh(x) = 1 - 2/(exp(2x)+1)
        const float z = __builtin_amdgcn_exp2f(2.8853900817779268f * a2);
        const float h = 1.f - 2.f * __builtin_amdgcn_rcpf(z + 1.f);
        pooled += h;

        if (lane < 32) lds[64 + lane] = h;
        asm volatile("s_waitcnt lgkmcnt(0)" ::: "memory");
#pragma unroll
        for (int i = 0; i < 8; ++i) {
            float4 hv = reinterpret_cast<const float4*>(lds + 64)[i];
            hfull[4*i] = hv.x; hfull[4*i+1] = hv.y; hfull[4*i+2] = hv.z; hfull[4*i+3] = hv.w;
        }
        xq = xq_next;
    }
    pooled *= (1.f / T);
    if (lane < 32) lds[lane] = pooled;
    asm volatile("s_waitcnt lgkmcnt(0)" ::: "memory");

    float wov[LAT];
#pragma unroll
    for (int i = 0; i < LAT; ++i) wov[i] = Wo[l * LAT + i];
    float a3 = bo[l];
#pragma unroll
    for (int i = 0; i < 8; ++i) {
        float4 pv = reinterpret_cast<const float4*>(lds)[i];
        a3 = fmaf(pv.x, wov[4*i], a3);   a3 = fmaf(pv.y, wov[4*i+1], a3);
        a3 = fmaf(pv.z, wov[4*i+2], a3); a3 = fmaf(pv.w, wov[4*i+3], a3);
    }
    if (lane < 32) out[(size_t)b * LAT + l] = a3;
}

extern "C" void kernel_launch(void* const* d_in, const int* in_sizes, int n_in,
                              void* d_out, int out_size, void* d_ws, size_t ws_size,
                              hipStream_t stream) {
    const float* x    = (const float*)d_in[0];
    const float* c1w  = (const float*)d_in[1];
    const float* c1b  = (const float*)d_in[2];
    const float* bn1g = (const float*)d_in[3];
    const float* bn1b = (const float*)d_in[4];
    const float* c2w  = (const float*)d_in[5];
    const float* c2b  = (const float*)d_in[6];
    const float* bn2g = (const float*)d_in[7];
    const float* bn2b = (const float*)d_in[8];
    const float* Wi   = (const float*)d_in[9];
    const float* bi   = (const float*)d_in[10];
    const float* ln1g = (const float*)d_in[11];
    const float* ln1b = (const float*)d_in[12];
    const float* Wh   = (const float*)d_in[13];
    const float* bh   = (const float*)d_in[14];
    const float* ln2g = (const float*)d_in[15];
    const float* ln2b = (const float*)d_in[16];
    const float* Wr   = (const float*)d_in[17];
    const float* br   = (const float*)d_in[18];
    const float* Wo   = (const float*)d_in[19];
    const float* bo   = (const float*)d_in[20];

    float* ws = (float*)d_ws;
    float* raw1 = ws;                // 2048 (S at o*16, Q at 1024+o*16)
    float* raw2 = ws + 2048;         // 2048
    float* fin1 = ws + 4096;         // 64 (scale[32], shift[32])
    float* fin2 = ws + 4160;         // 64
    float* wT1  = ws + 4224;         // 19200
    float* wT2  = ws + 23424;        // 25600
    float* y1   = ws + 49024;        // 512*32*496 = 8126464
    float* y2   = y1 + 8126464;      // [b][t][f] = 1556480
    float* xt2  = y1;                // alias y1 (dead after conv2): [T][B][HID] = 3112960 <= 8126464
    float* out  = (float*)d_out;

    hipMemsetAsync(raw1, 0, 4096 * sizeof(float), stream);
    k_transpose_w<<<175, 256, 0, stream>>>(c1w, c2w, wT1, wT2);
    k_conv1<<<dim3(4, B), 256, 0, stream>>>(x, wT1, c1b, y1, raw1);
    k_bnfin<<<1, 32, 0, stream>>>(raw1, bn1g, bn1b, fin1, (float)(B * L1));
    k_conv2<<<B, 256, 0, stream>>>(y1, wT2, c2b, fin1, y2, raw2);
    k_bnfin<<<1, 32, 0, stream>>>(raw2, bn2g, bn2b, fin2, (float)(B * L2));
    k_proj<<<(B * T + 255) / 256, 256, 0, stream>>>(y2, fin2, Wi, bi, ln1g, ln1b, Wh, bh, xt2);
    k_rnn<<<B, 64, 0, stream>>>(xt2, Wh, ln2g, ln2b, Wr, br, Wo, bo, out);
}

// Round 3
// 359.519 us; speedup vs baseline: 1.4818x; 1.1546x over previous
//
#include <hip/hip_runtime.h>

#define EPS 1e-5f

#define B    512
#define C_IN 12
#define L_IN 5000
#define C1   32
#define L1   496   // (5000-50)/10+1
#define NF   32
#define L2   95    // (496-25)/5+1
#define LAT  32
#define HID  64
#define T    L2

// ---------------- weight transpose: w[o][ck] -> wT[ck][o] ----------------
__global__ void k_transpose_w(const float* __restrict__ c1w, const float* __restrict__ c2w,
                              float* __restrict__ wT1, float* __restrict__ wT2) {
    int i = blockIdx.x * 256 + threadIdx.x;
    if (i < 19200) {                 // 12*50*32
        int ck = i >> 5, o = i & 31;
        wT1[i] = c1w[o * 600 + ck];
    } else if (i < 44800) {          // 32*25*32
        int j = i - 19200;
        int ck = j >> 5, o = j & 31;
        wT2[j] = c2w[o * 800 + ck];
    }
}

// ---------------- conv1 + bias + BN1 stats ----------------
// grid (2, B), 256 thr. thread = one t, ALL 32 oc in regs (64 FMA per ds_read_b64).
// per-channel double-buffered LDS (2 x 10.4KB), register-staged prefetch, 1 barrier/channel.
__global__ __launch_bounds__(256) void k_conv1(const float* __restrict__ x,
                                               const float* __restrict__ wT1,
                                               const float* __restrict__ c1b,
                                               float* __restrict__ y1,
                                               float* __restrict__ raw1) {
    __shared__ __align__(16) float xs[2][2600];
    const int chunk = blockIdx.x, b = blockIdx.y, tid = threadIdx.x;
    const int t0 = chunk * 256;
    const int nt = chunk ? (L1 - 256) : 256;          // 240 / 256
    const int nload4 = chunk ? 610 : 650;             // (nt*10+40)/4
    const bool active = tid < nt;
    const float* xb = x + (size_t)b * (C_IN * L_IN) + t0 * 10;

    // prologue: stage channel 0 into regs
    float4 r0, r1, r2;
    {
        const float4* s4 = reinterpret_cast<const float4*>(xb);
        if (tid < nload4)       r0 = s4[tid];
        if (tid + 256 < nload4) r1 = s4[tid + 256];
        if (tid + 512 < nload4) r2 = s4[tid + 512];
    }

    float acc[C1];
#pragma unroll
    for (int o = 0; o < C1; ++o) acc[o] = 0.f;
    const int xoff = active ? 10 * tid : 0;

    for (int c = 0; c < C_IN; ++c) {
        // write staged regs -> buf[c&1] (safe: last read of this buf was iter c-2,
        // guaranteed complete by the barrier in iter c-1)
        float4* buf4 = reinterpret_cast<float4*>(xs[c & 1]);
        if (tid < nload4)       buf4[tid] = r0;
        if (tid + 256 < nload4) buf4[tid + 256] = r1;
        if (tid + 512 < nload4) buf4[tid + 512] = r2;
        // issue next channel's global loads (latency hides under compute below)
        if (c + 1 < C_IN) {
            const float4* s4 = reinterpret_cast<const float4*>(xb + (c + 1) * L_IN);
            if (tid < nload4)       r0 = s4[tid];
            if (tid + 256 < nload4) r1 = s4[tid + 256];
            if (tid + 512 < nload4) r2 = s4[tid + 512];
        }
        __syncthreads();
        const float* xc = xs[c & 1] + xoff;
        const float* wc = wT1 + c * 1600;  // wave-uniform -> scalar loads
#pragma unroll 5
        for (int kk = 0; kk < 25; ++kk) {
            const float2 xv = *reinterpret_cast<const float2*>(xc + 2 * kk);
            const float* w0 = wc + kk * 64;
#pragma unroll
            for (int o = 0; o < C1; ++o) acc[o] = fmaf(xv.x, w0[o], acc[o]);
#pragma unroll
            for (int o = 0; o < C1; ++o) acc[o] = fmaf(xv.y, w0[32 + o], acc[o]);
        }
    }

    float val[C1];
#pragma unroll
    for (int o = 0; o < C1; ++o) val[o] = active ? (acc[o] + c1b[o]) : 0.f;
    if (active) {
        float* yrow = y1 + (size_t)b * (C1 * L1) + t0 + tid;
#pragma unroll
        for (int o = 0; o < C1; ++o) yrow[o * L1] = val[o];
    }

    // stats: wave shfl-reduce -> LDS (reuse xs[0], free since iter 10) -> 64 atomics
    float* redS = xs[0];         // [4][32]
    float* redQ = xs[0] + 128;   // [4][32]
    const int lane = tid & 63, wave = tid >> 6;
    for (int o = 0; o < C1; ++o) {
        float s = val[o], q = val[o] * val[o];
#pragma unroll
        for (int off = 32; off >= 1; off >>= 1) { s += __shfl_xor(s, off); q += __shfl_xor(q, off); }
        if (lane == 0) { redS[wave * 32 + o] = s; redQ[wave * 32 + o] = q; }
    }
    __syncthreads();
    if (tid < 64) {
        int o = tid & 31, isQ = tid >> 5;
        const float* red = isQ ? redQ : redS;
        float v = red[o] + red[32 + o] + red[64 + o] + red[96 + o];
        atomicAdd(&raw1[(isQ ? 1024 : 0) + o * 16], v);
    }
}

// ---------------- BN finalize: strided raw (sum,sumsq) -> compact (scale, shift) ----------------
__global__ void k_bnfin(const float* __restrict__ raw, const float* __restrict__ g,
                        const float* __restrict__ bb, float* __restrict__ fin, float count) {
    int o = threadIdx.x;
    if (o < 32) {
        float mean = raw[o * 16] / count;
        float var = raw[1024 + o * 16] / count - mean * mean;
        float sc = g[o] * rsqrtf(var + EPS);
        fin[o] = sc;
        fin[32 + o] = bb[o] - mean * sc;
    }
}

// ---------------- conv2 (+BN1+relu on input) + bias + BN2 stats ----------------
// grid B, 256 thr. thread = (t, oc-half). per-channel double-buffered LDS (2 x 2KB).
__global__ __launch_bounds__(256) void k_conv2(const float* __restrict__ y1,
                                               const float* __restrict__ wT2,
                                               const float* __restrict__ c2b,
                                               const float* __restrict__ fin1,
                                               float* __restrict__ y2,
                                               float* __restrict__ raw2) {
    __shared__ __align__(16) float xs[2][L1];  // 2 x 496 floats
    __shared__ float redS[4][16], redQ[4][16];
    const int b = blockIdx.x, tid = threadIdx.x;
    const int half = tid >> 7, tl = tid & 127;
    const int halfu = __builtin_amdgcn_readfirstlane(half);
    const bool active = tl < L2;
    const float* src = y1 + (size_t)b * (C1 * L1);

    float4 r;
    if (tid < 124) r = reinterpret_cast<const float4*>(src)[tid];

    float acc[16];
#pragma unroll
    for (int o = 0; o < 16; ++o) acc[o] = 0.f;
    const int xoff = active ? 5 * tl : 0;

    for (int c = 0; c < C1; ++c) {
        if (tid < 124) {
            const float sc = fin1[c], sh = fin1[32 + c];
            float4 d = r;
            d.x = fmaxf(fmaf(d.x, sc, sh), 0.f);
            d.y = fmaxf(fmaf(d.y, sc, sh), 0.f);
            d.z = fmaxf(fmaf(d.z, sc, sh), 0.f);
            d.w = fmaxf(fmaf(d.w, sc, sh), 0.f);
            reinterpret_cast<float4*>(xs[c & 1])[tid] = d;
        }
        if (c + 1 < C1 && tid < 124)
            r = reinterpret_cast<const float4*>(src + (c + 1) * L1)[tid];
        __syncthreads();
        const float* xc = xs[c & 1] + xoff;
        const float* wc = wT2 + c * 800 + halfu * 16;  // wave-uniform -> scalar loads
#pragma unroll 5
        for (int k = 0; k < 25; ++k) {
            const float xv = xc[k];
            const float* w0 = wc + k * 32;
#pragma unroll
            for (int o = 0; o < 16; ++o) acc[o] = fmaf(xv, w0[o], acc[o]);
        }
    }

    float val[16];
#pragma unroll
    for (int o = 0; o < 16; ++o) val[o] = active ? (acc[o] + c2b[halfu * 16 + o]) : 0.f;
    if (active) {
        float4* dst = reinterpret_cast<float4*>(y2 + ((size_t)b * L2 + tl) * NF + halfu * 16);
#pragma unroll
        for (int o4 = 0; o4 < 4; ++o4)
            dst[o4] = make_float4(val[4 * o4], val[4 * o4 + 1], val[4 * o4 + 2], val[4 * o4 + 3]);
    }
    const int lane = tid & 63, wave = tid >> 6;
    for (int o = 0; o < 16; ++o) {
        float s = val[o], q = val[o] * val[o];
#pragma unroll
        for (int off = 32; off >= 1; off >>= 1) { s += __shfl_xor(s, off); q += __shfl_xor(q, off); }
        if (lane == 0) { redS[wave][o] = s; redQ[wave][o] = q; }
    }
    __syncthreads();
    if (tid < 64) {
        int o = tid & 15, grp = (tid >> 4) & 1, isQ = tid >> 5;
        int oc = grp * 16 + o;
        float v = isQ ? (redQ[grp * 2][o] + redQ[grp * 2 + 1][o])
                      : (redS[grp * 2][o] + redS[grp * 2 + 1][o]);
        atomicAdd(&raw2[(isQ ? 1024 : 0) + oc * 16], v);
    }
}

// ---------------- BN2+relu, input proj, LN1, then fold Wh: xt2 = LN1(..)@Wh.T + bh ----------------
// xt2 layout [T][B][HID]
__global__ __launch_bounds__(256) void k_proj(const float* __restrict__ y2,
                                              const float* __restrict__ fin2,
                                              const float* __restrict__ Wi,
                                              const float* __restrict__ bi,
                                              const float* __restrict__ ln1g,
                                              const float* __restrict__ ln1b,
                                              const float* __restrict__ Wh,
                                              const float* __restrict__ bh,
                                              float* __restrict__ xt2) {
    const int r = blockIdx.x * 256 + threadIdx.x;
    if (r >= B * T) return;
    const int b = r / 95, t = r - b * 95;

    const float4* row = reinterpret_cast<const float4*>(y2 + (size_t)r * NF);
    float u[NF];
#pragma unroll
    for (int f4 = 0; f4 < 8; ++f4) {
        float4 v = row[f4];
        u[4*f4]   = fmaxf(fmaf(v.x, fin2[4*f4],   fin2[32 + 4*f4]),   0.f);
        u[4*f4+1] = fmaxf(fmaf(v.y, fin2[4*f4+1], fin2[32 + 4*f4+1]), 0.f);
        u[4*f4+2] = fmaxf(fmaf(v.z, fin2[4*f4+2], fin2[32 + 4*f4+2]), 0.f);
        u[4*f4+3] = fmaxf(fmaf(v.w, fin2[4*f4+3], fin2[32 + 4*f4+3]), 0.f);
    }
    float xln[LAT];
    float s = 0.f, q = 0.f;
#pragma unroll
    for (int l = 0; l < LAT; ++l) {
        float a = bi[l];
#pragma unroll
        for (int f = 0; f < NF; ++f) a = fmaf(u[f], Wi[l * NF + f], a);
        xln[l] = a; s += a; q += a * a;
    }
    const float m = s * (1.f / LAT);
    const float inv = rsqrtf(q * (1.f / LAT) - m * m + EPS);
#pragma unroll
    for (int l = 0; l < LAT; ++l) xln[l] = (xln[l] - m) * inv * ln1g[l] + ln1b[l];

    float4* dst = reinterpret_cast<float4*>(xt2 + ((size_t)t * B + b) * HID);
#pragma unroll
    for (int j4 = 0; j4 < 16; ++j4) {
        float4 o4;
        float a0 = bh[4*j4], a1 = bh[4*j4+1], a2 = bh[4*j4+2], a3 = bh[4*j4+3];
#pragma unroll
        for (int l = 0; l < LAT; ++l) {
            float xl = xln[l];
            a0 = fmaf(xl, Wh[(4*j4)   * LAT + l], a0);
            a1 = fmaf(xl, Wh[(4*j4+1) * LAT + l], a1);
            a2 = fmaf(xl, Wh[(4*j4+2) * LAT + l], a2);
            a3 = fmaf(xl, Wh[(4*j4+3) * LAT + l], a3);
        }
        o4.x = a0; o4.y = a1; o4.z = a2; o4.w = a3;
        dst[j4] = o4;
    }
}

// ---------------- RNN scan + pooled mean + final linear ----------------
// single-wave blocks (64 thr): no s_barrier, LDS ordering via lgkmcnt waits.
__global__ __launch_bounds__(64) void k_rnn(const float* __restrict__ xt2,
                                            const float* __restrict__ Wh,
                                            const float* __restrict__ ln2g,
                                            const float* __restrict__ ln2b,
                                            const float* __restrict__ Wr,
                                            const float* __restrict__ br,
                                            const float* __restrict__ Wo,
                                            const float* __restrict__ bo,
                                            float* __restrict__ out) {
    __shared__ __align__(16) float lds[96];  // [0..63] hp, [64..95] h
    const int lane = threadIdx.x;
    const int b = blockIdx.x;
    const int l = lane & 31;

    float whv[LAT];
#pragma unroll
    for (int i = 0; i < LAT; ++i) whv[i] = Wh[lane * LAT + i];
    float wrv[HID];
#pragma unroll
    for (int i = 0; i < HID; ++i) wrv[i] = Wr[l * HID + i];
    const float g_j = ln2g[lane], bb_j = ln2b[lane];
    const float br_l = br[l];

    float hfull[LAT];
#pragma unroll
    for (int i = 0; i < LAT; ++i) hfull[i] = 0.f;
    float pooled = 0.f;
    float xq = xt2[(size_t)b * HID + lane];  // t=0 (xt2 already = Wh@xt + bh)

    for (int t = 0; t < T; ++t) {
        float xq_next = 0.f;
        if (t + 1 < T) xq_next = xt2[((size_t)(t + 1) * B + b) * HID + lane];

        float a = xq;
#pragma unroll
        for (int i = 0; i < LAT; ++i) a = fmaf(hfull[i], whv[i], a);
        a = fmaxf(a, 0.f);
        float s = a, q = a * a;
#pragma unroll
        for (int off = 32; off >= 1; off >>= 1) { s += __shfl_xor(s, off); q += __shfl_xor(q, off); }
        const float m = s * (1.f / HID);
        const float inv = __builtin_amdgcn_rsqf(q * (1.f / HID) - m * m + EPS);
        const float hpv = (a - m) * inv * g_j + bb_j;

        lds[lane] = hpv;
        asm volatile("s_waitcnt lgkmcnt(0)" ::: "memory");
        float a2 = br_l;
#pragma unroll
        for (int i = 0; i < 16; ++i) {
            float4 hv = reinterpret_cast<const float4*>(lds)[i];
            a2 = fmaf(hv.x, wrv[4*i], a2);   a2 = fmaf(hv.y, wrv[4*i+1], a2);
            a2 = fmaf(hv.z, wrv[4*i+2], a2); a2 = fmaf(hv.w, wrv[4*i+3], a2);
        }
        // tanh via native exp2/rcp: tanh(x) = 1 - 2/(exp(2x)+1)
        const float z = __builtin_amdgcn_exp2f(2.8853900817779268f * a2);
        const float h = 1.f - 2.f * __builtin_amdgcn_rcpf(z + 1.f);
        pooled += h;

        if (lane < 32) lds[64 + lane] = h;
        asm volatile("s_waitcnt lgkmcnt(0)" ::: "memory");
#pragma unroll
        for (int i = 0; i < 8; ++i) {
            float4 hv = reinterpret_cast<const float4*>(lds + 64)[i];
            hfull[4*i] = hv.x; hfull[4*i+1] = hv.y; hfull[4*i+2] = hv.z; hfull[4*i+3] = hv.w;
        }
        xq = xq_next;
    }
    pooled *= (1.f / T);
    if (lane < 32) lds[lane] = pooled;
    asm volatile("s_waitcnt lgkmcnt(0)" ::: "memory");

    float wov[LAT];
#pragma unroll
    for (int i = 0; i < LAT; ++i) wov[i] = Wo[l * LAT + i];
    float a3 = bo[l];
#pragma unroll
    for (int i = 0; i < 8; ++i) {
        float4 pv = reinterpret_cast<const float4*>(lds)[i];
        a3 = fmaf(pv.x, wov[4*i], a3);   a3 = fmaf(pv.y, wov[4*i+1], a3);
        a3 = fmaf(pv.z, wov[4*i+2], a3); a3 = fmaf(pv.w, wov[4*i+3], a3);
    }
    if (lane < 32) out[(size_t)b * LAT + l] = a3;
}

extern "C" void kernel_launch(void* const* d_in, const int* in_sizes, int n_in,
                              void* d_out, int out_size, void* d_ws, size_t ws_size,
                              hipStream_t stream) {
    const float* x    = (const float*)d_in[0];
    const float* c1w  = (const float*)d_in[1];
    const float* c1b  = (const float*)d_in[2];
    const float* bn1g = (const float*)d_in[3];
    const float* bn1b = (const float*)d_in[4];
    const float* c2w  = (const float*)d_in[5];
    const float* c2b  = (const float*)d_in[6];
    const float* bn2g = (const float*)d_in[7];
    const float* bn2b = (const float*)d_in[8];
    const float* Wi   = (const float*)d_in[9];
    const float* bi   = (const float*)d_in[10];
    const float* ln1g = (const float*)d_in[11];
    const float* ln1b = (const float*)d_in[12];
    const float* Wh   = (const float*)d_in[13];
    const float* bh   = (const float*)d_in[14];
    const float* ln2g = (const float*)d_in[15];
    const float* ln2b = (const float*)d_in[16];
    const float* Wr   = (const float*)d_in[17];
    const float* br   = (const float*)d_in[18];
    const float* Wo   = (const float*)d_in[19];
    const float* bo   = (const float*)d_in[20];

    float* ws = (float*)d_ws;
    float* raw1 = ws;                // 2048 (S at o*16, Q at 1024+o*16)
    float* raw2 = ws + 2048;         // 2048
    float* fin1 = ws + 4096;         // 64 (scale[32], shift[32])
    float* fin2 = ws + 4160;         // 64
    float* wT1  = ws + 4224;         // 19200
    float* wT2  = ws + 23424;        // 25600
    float* y1   = ws + 49024;        // 512*32*496 = 8126464
    float* y2   = y1 + 8126464;      // [b][t][f] = 1556480
    float* xt2  = y1;                // alias y1 (dead after conv2): [T][B][HID] = 3112960 <= 8126464
    float* out  = (float*)d_out;

    hipMemsetAsync(raw1, 0, 4096 * sizeof(float), stream);
    k_transpose_w<<<175, 256, 0, stream>>>(c1w, c2w, wT1, wT2);
    k_conv1<<<dim3(2, B), 256, 0, stream>>>(x, wT1, c1b, y1, raw1);
    k_bnfin<<<1, 32, 0, stream>>>(raw1, bn1g, bn1b, fin1, (float)(B * L1));
    k_conv2<<<B, 256, 0, stream>>>(y1, wT2, c2b, fin1, y2, raw2);
    k_bnfin<<<1, 32, 0, stream>>>(raw2, bn2g, bn2b, fin2, (float)(B * L2));
    k_proj<<<(B * T + 255) / 256, 256, 0, stream>>>(y2, fin2, Wi, bi, ln1g, ln1b, Wh, bh, xt2);
    k_rnn<<<B, 64, 0, stream>>>(xt2, Wh, ln2g, ln2b, Wr, br, Wo, bo, out);
}

// Round 4
// 311.892 us; speedup vs baseline: 1.7081x; 1.1527x over previous
//
#include <hip/hip_runtime.h>

#define EPS 1e-5f

#define B    512
#define C_IN 12
#define L_IN 5000
#define C1   32
#define L1   496   // (5000-50)/10+1
#define NF   32
#define L2   95    // (496-25)/5+1
#define LAT  32
#define HID  64
#define T    L2

typedef short s16x8 __attribute__((ext_vector_type(8)));
typedef float f32x16 __attribute__((ext_vector_type(16)));

__device__ __forceinline__ ushort f2bf(float f) {   // RNE float->bf16 bits
    uint u = __builtin_bit_cast(uint, f);
    u += 0x7fff + ((u >> 16) & 1);
    return (ushort)(u >> 16);
}
__device__ __forceinline__ float bf2f(ushort h) {
    return __builtin_bit_cast(float, (uint)h << 16);
}

// ---------------- weight prep ----------------
// wfrag: conv1 weights in MFMA B-fragment lane order, bf16 hi/lo, kk padded to 64.
// uint4 index = ((c*4 + s)*2 + split)*64 + lane ; lane: col=lane&31=oc, k=s*16+(lane>>5)*8+i
__global__ void k_prep_w(const float* __restrict__ c1w, const float* __restrict__ c2w,
                         ushort* __restrict__ wfrag, float* __restrict__ wT2) {
    int i = blockIdx.x * 256 + threadIdx.x;
    if (i < 6144) {
        int lane = i & 63, r = i >> 6;
        int split = r & 1, s = (r >> 1) & 3, c = r >> 3;
        int oc = lane & 31, kbase = s * 16 + (lane >> 5) * 8;
        ushort o8[8];
#pragma unroll
        for (int j = 0; j < 8; ++j) {
            int kk = kbase + j;
            float w = (kk < 50) ? c1w[oc * 600 + c * 50 + kk] : 0.f;
            ushort hb = f2bf(w);
            o8[j] = split ? f2bf(w - bf2f(hb)) : hb;
        }
        ushort4* dst = reinterpret_cast<ushort4*>(wfrag) + (size_t)i * 2;
        dst[0] = make_ushort4(o8[0], o8[1], o8[2], o8[3]);
        dst[1] = make_ushort4(o8[4], o8[5], o8[6], o8[7]);
    } else if (i < 31744) {           // 32*25*32 conv2 transpose (fp32)
        int j = i - 6144;
        int ck = j >> 5, o = j & 31;
        wT2[j] = c2w[o * 800 + ck];
    }
}

// ---------------- conv1 via split-bf16 MFMA + bias + BN1 stats ----------------
// grid (4, B), 256 thr = 4 waves; each wave owns one 32x32 C-tile (32 t x 32 oc).
// per-channel K=64 (weights zero-padded), x staged bf16 hi/lo, double-buffered LDS.
__global__ __launch_bounds__(256) void k_conv1(const float* __restrict__ x,
                                               const ushort* __restrict__ wfrag,
                                               const float* __restrict__ c1b,
                                               float* __restrict__ y1,
                                               float* __restrict__ raw1) {
    __shared__ ushort xh[2][1344];
    __shared__ ushort xl[2][1344];
    __shared__ float redS[4][32], redQ[4][32];
    const int chunk = blockIdx.x, b = blockIdx.y, tid = threadIdx.x;
    const int t0 = chunk * 128;
    const int v4max = min(336, (5000 - 10 * t0) >> 2);   // chunk3: 290
    const float* xbase = x + (size_t)b * (C_IN * L_IN) + 10 * t0;

    // prologue: stage channel 0 into regs (zeros where OOB)
    float4 r0 = make_float4(0, 0, 0, 0), r1 = make_float4(0, 0, 0, 0);
    {
        const float4* s4 = reinterpret_cast<const float4*>(xbase);
        if (tid < v4max) r0 = s4[tid];
        if (tid + 256 < v4max) r1 = s4[tid + 256];
    }

    const int lane = tid & 63, wv = tid >> 6;
    const int cl = lane & 31;          // A-row (t) and C-col (oc)
    const int kgrp = lane >> 5;        // 0/1: k-subgroup
    const int abase = 10 * (wv * 32 + cl) + kgrp * 8;

    f32x16 acc;
#pragma unroll
    for (int i = 0; i < 16; ++i) acc[i] = 0.f;

    const uint4* wf4 = reinterpret_cast<const uint4*>(wfrag);

    for (int c = 0; c < C_IN; ++c) {
        const int p = c & 1;
        // convert staged regs -> bf16 hi/lo, write LDS (zeros beyond valid region)
        if (tid < 336) {
            ushort4 h4, l4;
            h4.x = f2bf(r0.x); l4.x = f2bf(r0.x - bf2f(h4.x));
            h4.y = f2bf(r0.y); l4.y = f2bf(r0.y - bf2f(h4.y));
            h4.z = f2bf(r0.z); l4.z = f2bf(r0.z - bf2f(h4.z));
            h4.w = f2bf(r0.w); l4.w = f2bf(r0.w - bf2f(h4.w));
            *reinterpret_cast<ushort4*>(&xh[p][4 * tid]) = h4;
            *reinterpret_cast<ushort4*>(&xl[p][4 * tid]) = l4;
        }
        if (tid + 256 < 336) {
            ushort4 h4, l4;
            h4.x = f2bf(r1.x); l4.x = f2bf(r1.x - bf2f(h4.x));
            h4.y = f2bf(r1.y); l4.y = f2bf(r1.y - bf2f(h4.y));
            h4.z = f2bf(r1.z); l4.z = f2bf(r1.z - bf2f(h4.z));
            h4.w = f2bf(r1.w); l4.w = f2bf(r1.w - bf2f(h4.w));
            *reinterpret_cast<ushort4*>(&xh[p][4 * (tid + 256)]) = h4;
            *reinterpret_cast<ushort4*>(&xl[p][4 * (tid + 256)]) = l4;
        }
        // prefetch next channel
        if (c + 1 < C_IN) {
            const float4* s4 = reinterpret_cast<const float4*>(xbase + (size_t)(c + 1) * L_IN);
            r0 = make_float4(0, 0, 0, 0); r1 = make_float4(0, 0, 0, 0);
            if (tid < v4max) r0 = s4[tid];
            if (tid + 256 < v4max) r1 = s4[tid + 256];
        }
        __syncthreads();

        const ushort* ph = xh[p];
        const ushort* pl = xl[p];
        const uint4* wc = wf4 + (size_t)c * 512 + lane;
#pragma unroll
        for (int s = 0; s < 4; ++s) {
            const int idx = abase + s * 16;    // always even -> 4B aligned
            union { s16x8 v; uint u[4]; } ah, al, bh, bl;
            ah.u[0] = *reinterpret_cast<const uint*>(&ph[idx]);
            ah.u[1] = *reinterpret_cast<const uint*>(&ph[idx + 2]);
            ah.u[2] = *reinterpret_cast<const uint*>(&ph[idx + 4]);
            ah.u[3] = *reinterpret_cast<const uint*>(&ph[idx + 6]);
            al.u[0] = *reinterpret_cast<const uint*>(&pl[idx]);
            al.u[1] = *reinterpret_cast<const uint*>(&pl[idx + 2]);
            al.u[2] = *reinterpret_cast<const uint*>(&pl[idx + 4]);
            al.u[3] = *reinterpret_cast<const uint*>(&pl[idx + 6]);
            uint4 bq = wc[s * 128];            // hi split
            uint4 lq = wc[s * 128 + 64];       // lo split
            bh.u[0] = bq.x; bh.u[1] = bq.y; bh.u[2] = bq.z; bh.u[3] = bq.w;
            bl.u[0] = lq.x; bl.u[1] = lq.y; bl.u[2] = lq.z; bl.u[3] = lq.w;
            acc = __builtin_amdgcn_mfma_f32_32x32x16_bf16(ah.v, bh.v, acc, 0, 0, 0);
            acc = __builtin_amdgcn_mfma_f32_32x32x16_bf16(ah.v, bl.v, acc, 0, 0, 0);
            acc = __builtin_amdgcn_mfma_f32_32x32x16_bf16(al.v, bh.v, acc, 0, 0, 0);
        }
    }

    // epilogue: bias, store (C-row = (reg&3)+8*(reg>>2)+4*kgrp), stats
    const float bias = c1b[cl];
    float sum = 0.f, sq = 0.f;
    float* yb = y1 + ((size_t)b * C1 + cl) * L1;
#pragma unroll
    for (int q = 0; q < 4; ++q) {
        const int trow = t0 + wv * 32 + 8 * q + 4 * kgrp;
        float4 st;
        st.x = acc[4 * q + 0] + bias;
        st.y = acc[4 * q + 1] + bias;
        st.z = acc[4 * q + 2] + bias;
        st.w = acc[4 * q + 3] + bias;
        if (trow < L1) {
            *reinterpret_cast<float4*>(yb + trow) = st;
            sum += st.x + st.y + st.z + st.w;
            sq  += st.x * st.x + st.y * st.y + st.z * st.z + st.w * st.w;
        }
    }
    sum += __shfl_xor(sum, 32);
    sq  += __shfl_xor(sq, 32);
    if (lane < 32) { redS[wv][cl] = sum; redQ[wv][cl] = sq; }
    __syncthreads();
    if (tid < 64) {
        int o = tid & 31, isQ = tid >> 5;
        float v = isQ ? (redQ[0][o] + redQ[1][o] + redQ[2][o] + redQ[3][o])
                      : (redS[0][o] + redS[1][o] + redS[2][o] + redS[3][o]);
        atomicAdd(&raw1[(isQ ? 1024 : 0) + o * 16], v);
    }
}

// ---------------- BN finalize ----------------
__global__ void k_bnfin(const float* __restrict__ raw, const float* __restrict__ g,
                        const float* __restrict__ bb, float* __restrict__ fin, float count) {
    int o = threadIdx.x;
    if (o < 32) {
        float mean = raw[o * 16] / count;
        float var = raw[1024 + o * 16] / count - mean * mean;
        float sc = g[o] * rsqrtf(var + EPS);
        fin[o] = sc;
        fin[32 + o] = bb[o] - mean * sc;
    }
}

// ---------------- conv2 (+BN1+relu on input) + bias + BN2 stats ----------------
// grid (2, B), 256 thr. t-chunks of 48/47; thread = (t, oc-half); per-channel dbuf LDS.
__global__ __launch_bounds__(256) void k_conv2(const float* __restrict__ y1,
                                               const float* __restrict__ wT2,
                                               const float* __restrict__ c2b,
                                               const float* __restrict__ fin1,
                                               float* __restrict__ y2,
                                               float* __restrict__ raw2) {
    __shared__ __align__(16) float xs[2][272];
    __shared__ float redS[4][16], redQ[4][16];
    const int chunk = blockIdx.x, b = blockIdx.y, tid = threadIdx.x;
    const int t0 = chunk * 48;
    const int nt = chunk ? 47 : 48;
    const int nload4 = chunk ? 64 : 66;
    const float* src = y1 + (size_t)b * (C1 * L1) + 5 * t0;

    float4 r = make_float4(0, 0, 0, 0);
    if (tid < nload4) r = reinterpret_cast<const float4*>(src)[tid];

    const int half = tid >> 7, tl = tid & 127;
    const int halfu = __builtin_amdgcn_readfirstlane(half);
    const bool active = tl < nt;
    const int xoff = active ? 5 * tl : 0;

    float acc[16];
#pragma unroll
    for (int o = 0; o < 16; ++o) acc[o] = 0.f;

    for (int c = 0; c < C1; ++c) {
        if (tid < nload4) {
            const float sc = fin1[c], sh = fin1[32 + c];
            float4 d;
            d.x = fmaxf(fmaf(r.x, sc, sh), 0.f);
            d.y = fmaxf(fmaf(r.y, sc, sh), 0.f);
            d.z = fmaxf(fmaf(r.z, sc, sh), 0.f);
            d.w = fmaxf(fmaf(r.w, sc, sh), 0.f);
            reinterpret_cast<float4*>(xs[c & 1])[tid] = d;
        }
        if (c + 1 < C1 && tid < nload4)
            r = reinterpret_cast<const float4*>(src + (size_t)(c + 1) * L1)[tid];
        __syncthreads();
        const float* xc = xs[c & 1] + xoff;
        const float* wc = wT2 + c * 800 + halfu * 16;   // wave-uniform -> scalar loads
#pragma unroll 5
        for (int k = 0; k < 25; ++k) {
            const float xv = xc[k];
            const float* w0 = wc + k * 32;
#pragma unroll
            for (int o = 0; o < 16; ++o) acc[o] = fmaf(xv, w0[o], acc[o]);
        }
    }

    float val[16];
#pragma unroll
    for (int o = 0; o < 16; ++o) val[o] = active ? (acc[o] + c2b[halfu * 16 + o]) : 0.f;
    if (active) {
        float4* dst = reinterpret_cast<float4*>(y2 + ((size_t)b * L2 + t0 + tl) * NF + halfu * 16);
#pragma unroll
        for (int o4 = 0; o4 < 4; ++o4)
            dst[o4] = make_float4(val[4 * o4], val[4 * o4 + 1], val[4 * o4 + 2], val[4 * o4 + 3]);
    }
    const int lane = tid & 63, wave = tid >> 6;
    for (int o = 0; o < 16; ++o) {
        float s = val[o], q = val[o] * val[o];
#pragma unroll
        for (int off = 32; off >= 1; off >>= 1) { s += __shfl_xor(s, off); q += __shfl_xor(q, off); }
        if (lane == 0) { redS[wave][o] = s; redQ[wave][o] = q; }
    }
    __syncthreads();
    if (tid < 64) {
        int o = tid & 15, grp = (tid >> 4) & 1, isQ = tid >> 5;
        int oc = grp * 16 + o;
        float v = isQ ? (redQ[grp * 2][o] + redQ[grp * 2 + 1][o])
                      : (redS[grp * 2][o] + redS[grp * 2 + 1][o]);
        atomicAdd(&raw2[(isQ ? 1024 : 0) + oc * 16], v);
    }
}

// ---------------- BN2+relu, input proj, LN1, fold Wh: xt2 = LN1(..)@Wh.T + bh ----------------
__global__ __launch_bounds__(256) void k_proj(const float* __restrict__ y2,
                                              const float* __restrict__ fin2,
                                              const float* __restrict__ Wi,
                                              const float* __restrict__ bi,
                                              const float* __restrict__ ln1g,
                                              const float* __restrict__ ln1b,
                                              const float* __restrict__ Wh,
                                              const float* __restrict__ bh,
                                              float* __restrict__ xt2) {
    const int r = blockIdx.x * 256 + threadIdx.x;
    if (r >= B * T) return;
    const int b = r / 95, t = r - b * 95;

    const float4* row = reinterpret_cast<const float4*>(y2 + (size_t)r * NF);
    float u[NF];
#pragma unroll
    for (int f4 = 0; f4 < 8; ++f4) {
        float4 v = row[f4];
        u[4*f4]   = fmaxf(fmaf(v.x, fin2[4*f4],   fin2[32 + 4*f4]),   0.f);
        u[4*f4+1] = fmaxf(fmaf(v.y, fin2[4*f4+1], fin2[32 + 4*f4+1]), 0.f);
        u[4*f4+2] = fmaxf(fmaf(v.z, fin2[4*f4+2], fin2[32 + 4*f4+2]), 0.f);
        u[4*f4+3] = fmaxf(fmaf(v.w, fin2[4*f4+3], fin2[32 + 4*f4+3]), 0.f);
    }
    float xln[LAT];
    float s = 0.f, q = 0.f;
#pragma unroll
    for (int l = 0; l < LAT; ++l) {
        float a = bi[l];
#pragma unroll
        for (int f = 0; f < NF; ++f) a = fmaf(u[f], Wi[l * NF + f], a);
        xln[l] = a; s += a; q += a * a;
    }
    const float m = s * (1.f / LAT);
    const float inv = rsqrtf(q * (1.f / LAT) - m * m + EPS);
#pragma unroll
    for (int l = 0; l < LAT; ++l) xln[l] = (xln[l] - m) * inv * ln1g[l] + ln1b[l];

    float4* dst = reinterpret_cast<float4*>(xt2 + ((size_t)t * B + b) * HID);
#pragma unroll
    for (int j4 = 0; j4 < 16; ++j4) {
        float4 o4;
        float a0 = bh[4*j4], a1 = bh[4*j4+1], a2 = bh[4*j4+2], a3 = bh[4*j4+3];
#pragma unroll
        for (int l = 0; l < LAT; ++l) {
            float xl = xln[l];
            a0 = fmaf(xl, Wh[(4*j4)   * LAT + l], a0);
            a1 = fmaf(xl, Wh[(4*j4+1) * LAT + l], a1);
            a2 = fmaf(xl, Wh[(4*j4+2) * LAT + l], a2);
            a3 = fmaf(xl, Wh[(4*j4+3) * LAT + l], a3);
        }
        o4.x = a0; o4.y = a1; o4.z = a2; o4.w = a3;
        dst[j4] = o4;
    }
}

// ---------------- RNN scan + pooled mean + final linear ----------------
__global__ __launch_bounds__(64) void k_rnn(const float* __restrict__ xt2,
                                            const float* __restrict__ Wh,
                                            const float* __restrict__ ln2g,
                                            const float* __restrict__ ln2b,
                                            const float* __restrict__ Wr,
                                            const float* __restrict__ br,
                                            const float* __restrict__ Wo,
                                            const float* __restrict__ bo,
                                            float* __restrict__ out) {
    __shared__ __align__(16) float lds[96];
    const int lane = threadIdx.x;
    const int b = blockIdx.x;
    const int l = lane & 31;

    float whv[LAT];
#pragma unroll
    for (int i = 0; i < LAT; ++i) whv[i] = Wh[lane * LAT + i];
    float wrv[HID];
#pragma unroll
    for (int i = 0; i < HID; ++i) wrv[i] = Wr[l * HID + i];
    const float g_j = ln2g[lane], bb_j = ln2b[lane];
    const float br_l = br[l];

    float hfull[LAT];
#pragma unroll
    for (int i = 0; i < LAT; ++i) hfull[i] = 0.f;
    float pooled = 0.f;
    float xq = xt2[(size_t)b * HID + lane];

    for (int t = 0; t < T; ++t) {
        float xq_next = 0.f;
        if (t + 1 < T) xq_next = xt2[((size_t)(t + 1) * B + b) * HID + lane];

        float a = xq;
#pragma unroll
        for (int i = 0; i < LAT; ++i) a = fmaf(hfull[i], whv[i], a);
        a = fmaxf(a, 0.f);
        float s = a, q = a * a;
#pragma unroll
        for (int off = 32; off >= 1; off >>= 1) { s += __shfl_xor(s, off); q += __shfl_xor(q, off); }
        const float m = s * (1.f / HID);
        const float inv = __builtin_amdgcn_rsqf(q * (1.f / HID) - m * m + EPS);
        const float hpv = (a - m) * inv * g_j + bb_j;

        lds[lane] = hpv;
        asm volatile("s_waitcnt lgkmcnt(0)" ::: "memory");
        float a2 = br_l;
#pragma unroll
        for (int i = 0; i < 16; ++i) {
            float4 hv = reinterpret_cast<const float4*>(lds)[i];
            a2 = fmaf(hv.x, wrv[4*i], a2);   a2 = fmaf(hv.y, wrv[4*i+1], a2);
            a2 = fmaf(hv.z, wrv[4*i+2], a2); a2 = fmaf(hv.w, wrv[4*i+3], a2);
        }
        const float z = __builtin_amdgcn_exp2f(2.8853900817779268f * a2);
        const float h = 1.f - 2.f * __builtin_amdgcn_rcpf(z + 1.f);
        pooled += h;

        if (lane < 32) lds[64 + lane] = h;
        asm volatile("s_waitcnt lgkmcnt(0)" ::: "memory");
#pragma unroll
        for (int i = 0; i < 8; ++i) {
            float4 hv = reinterpret_cast<const float4*>(lds + 64)[i];
            hfull[4*i] = hv.x; hfull[4*i+1] = hv.y; hfull[4*i+2] = hv.z; hfull[4*i+3] = hv.w;
        }
        xq = xq_next;
    }
    pooled *= (1.f / T);
    if (lane < 32) lds[lane] = pooled;
    asm volatile("s_waitcnt lgkmcnt(0)" ::: "memory");

    float wov[LAT];
#pragma unroll
    for (int i = 0; i < LAT; ++i) wov[i] = Wo[l * LAT + i];
    float a3 = bo[l];
#pragma unroll
    for (int i = 0; i < 8; ++i) {
        float4 pv = reinterpret_cast<const float4*>(lds)[i];
        a3 = fmaf(pv.x, wov[4*i], a3);   a3 = fmaf(pv.y, wov[4*i+1], a3);
        a3 = fmaf(pv.z, wov[4*i+2], a3); a3 = fmaf(pv.w, wov[4*i+3], a3);
    }
    if (lane < 32) out[(size_t)b * LAT + l] = a3;
}

extern "C" void kernel_launch(void* const* d_in, const int* in_sizes, int n_in,
                              void* d_out, int out_size, void* d_ws, size_t ws_size,
                              hipStream_t stream) {
    const float* x    = (const float*)d_in[0];
    const float* c1w  = (const float*)d_in[1];
    const float* c1b  = (const float*)d_in[2];
    const float* bn1g = (const float*)d_in[3];
    const float* bn1b = (const float*)d_in[4];
    const float* c2w  = (const float*)d_in[5];
    const float* c2b  = (const float*)d_in[6];
    const float* bn2g = (const float*)d_in[7];
    const float* bn2b = (const float*)d_in[8];
    const float* Wi   = (const float*)d_in[9];
    const float* bi   = (const float*)d_in[10];
    const float* ln1g = (const float*)d_in[11];
    const float* ln1b = (const float*)d_in[12];
    const float* Wh   = (const float*)d_in[13];
    const float* bh   = (const float*)d_in[14];
    const float* ln2g = (const float*)d_in[15];
    const float* ln2b = (const float*)d_in[16];
    const float* Wr   = (const float*)d_in[17];
    const float* br   = (const float*)d_in[18];
    const float* Wo   = (const float*)d_in[19];
    const float* bo   = (const float*)d_in[20];

    float* ws = (float*)d_ws;
    float* raw1 = ws;                    // 2048
    float* raw2 = ws + 2048;             // 2048
    float* fin1 = ws + 4096;             // 64
    float* fin2 = ws + 4160;             // 64
    float* wT2  = ws + 4224;             // 25600 -> ends 29824
    float* y1   = ws + 29824;            // 8126464 -> ends 8156288
    float* y2   = ws + 8156288;          // 1556480 -> ends 9712768
    ushort* wfrag = (ushort*)y2;         // 98304 B overlay; dead before conv2 writes y2
    float* xt2  = y1;                    // alias y1 (dead after conv2)
    float* out  = (float*)d_out;

    hipMemsetAsync(raw1, 0, 4096 * sizeof(float), stream);
    k_prep_w<<<124, 256, 0, stream>>>(c1w, c2w, wfrag, wT2);
    k_conv1<<<dim3(4, B), 256, 0, stream>>>(x, wfrag, c1b, y1, raw1);
    k_bnfin<<<1, 32, 0, stream>>>(raw1, bn1g, bn1b, fin1, (float)(B * L1));
    k_conv2<<<dim3(2, B), 256, 0, stream>>>(y1, wT2, c2b, fin1, y2, raw2);
    k_bnfin<<<1, 32, 0, stream>>>(raw2, bn2g, bn2b, fin2, (float)(B * L2));
    k_proj<<<(B * T + 255) / 256, 256, 0, stream>>>(y2, fin2, Wi, bi, ln1g, ln1b, Wh, bh, xt2);
    k_rnn<<<B, 64, 0, stream>>>(xt2, Wh, ln2g, ln2b, Wr, br, Wo, bo, out);
}

// Round 5
// 232.667 us; speedup vs baseline: 2.2897x; 1.3405x over previous
//
#include <hip/hip_runtime.h>

#define EPS 1e-5f

#define B    512
#define C_IN 12
#define L_IN 5000
#define C1   32
#define L1   496   // (5000-50)/10+1
#define NF   32
#define L2   95    // (496-25)/5+1
#define LAT  32
#define HID  64
#define T    L2

typedef short s16x8 __attribute__((ext_vector_type(8)));
typedef float f32x16 __attribute__((ext_vector_type(16)));

__device__ __forceinline__ ushort f2bf(float f) {   // RNE float->bf16 bits
    uint u = __builtin_bit_cast(uint, f);
    u += 0x7fff + ((u >> 16) & 1);
    return (ushort)(u >> 16);
}
__device__ __forceinline__ float bf2f(ushort h) {
    return __builtin_bit_cast(float, (uint)h << 16);
}

// ---------------- weight prep ----------------
// wfrag1: conv1 weights, B-frag order, K padded 50->64: ((c*4+s)*2+split)*64+lane
// wfrag2: conv2 weights, B-frag order, K padded 25->32: ((c*2+ks)*2+split)*64+lane
__global__ void k_prep_w(const float* __restrict__ c1w, const float* __restrict__ c2w,
                         ushort* __restrict__ wfrag1, ushort* __restrict__ wfrag2) {
    int i = blockIdx.x * 256 + threadIdx.x;
    if (i < 6144) {
        int lane = i & 63, r = i >> 6;
        int split = r & 1, s = (r >> 1) & 3, c = r >> 3;
        int oc = lane & 31, kbase = s * 16 + (lane >> 5) * 8;
        ushort o8[8];
#pragma unroll
        for (int j = 0; j < 8; ++j) {
            int kk = kbase + j;
            float w = (kk < 50) ? c1w[oc * 600 + c * 50 + kk] : 0.f;
            ushort hb = f2bf(w);
            o8[j] = split ? f2bf(w - bf2f(hb)) : hb;
        }
        ushort4* dst = reinterpret_cast<ushort4*>(wfrag1) + (size_t)i * 2;
        dst[0] = make_ushort4(o8[0], o8[1], o8[2], o8[3]);
        dst[1] = make_ushort4(o8[4], o8[5], o8[6], o8[7]);
    } else if (i < 14336) {
        int j = i - 6144;
        int lane = j & 63, r = j >> 6;
        int split = r & 1, ks = (r >> 1) & 1, c = r >> 2;
        int oc = lane & 31, kbase = ks * 16 + (lane >> 5) * 8;
        ushort o8[8];
#pragma unroll
        for (int jj = 0; jj < 8; ++jj) {
            int kk = kbase + jj;
            float w = (kk < 25) ? c2w[oc * 800 + c * 25 + kk] : 0.f;
            ushort hb = f2bf(w);
            o8[jj] = split ? f2bf(w - bf2f(hb)) : hb;
        }
        ushort4* dst = reinterpret_cast<ushort4*>(wfrag2) + (size_t)j * 2;
        dst[0] = make_ushort4(o8[0], o8[1], o8[2], o8[3]);
        dst[1] = make_ushort4(o8[4], o8[5], o8[6], o8[7]);
    }
}

// ---------------- conv1 via split-bf16 MFMA + bias + BN1 stats ----------------
// grid (4, B), 256 thr = 4 waves; each wave owns one 32x32 C-tile (32 t x 32 oc).
__global__ __launch_bounds__(256) void k_conv1(const float* __restrict__ x,
                                               const ushort* __restrict__ wfrag,
                                               const float* __restrict__ c1b,
                                               float* __restrict__ y1,
                                               float* __restrict__ raw1) {
    __shared__ ushort xh[2][1344];
    __shared__ ushort xl[2][1344];
    __shared__ float redS[4][32], redQ[4][32];
    const int chunk = blockIdx.x, b = blockIdx.y, tid = threadIdx.x;
    const int t0 = chunk * 128;
    const int v4max = min(336, (5000 - 10 * t0) >> 2);   // chunk3: 290
    const float* xbase = x + (size_t)b * (C_IN * L_IN) + 10 * t0;

    float4 r0 = make_float4(0, 0, 0, 0), r1 = make_float4(0, 0, 0, 0);
    {
        const float4* s4 = reinterpret_cast<const float4*>(xbase);
        if (tid < v4max) r0 = s4[tid];
        if (tid + 256 < v4max) r1 = s4[tid + 256];
    }

    const int lane = tid & 63, wv = tid >> 6;
    const int cl = lane & 31;
    const int kgrp = lane >> 5;
    const int abase = 10 * (wv * 32 + cl) + kgrp * 8;

    f32x16 acc;
#pragma unroll
    for (int i = 0; i < 16; ++i) acc[i] = 0.f;

    const uint4* wf4 = reinterpret_cast<const uint4*>(wfrag);

    for (int c = 0; c < C_IN; ++c) {
        const int p = c & 1;
        if (tid < 336) {
            ushort4 h4, l4;
            h4.x = f2bf(r0.x); l4.x = f2bf(r0.x - bf2f(h4.x));
            h4.y = f2bf(r0.y); l4.y = f2bf(r0.y - bf2f(h4.y));
            h4.z = f2bf(r0.z); l4.z = f2bf(r0.z - bf2f(h4.z));
            h4.w = f2bf(r0.w); l4.w = f2bf(r0.w - bf2f(h4.w));
            *reinterpret_cast<ushort4*>(&xh[p][4 * tid]) = h4;
            *reinterpret_cast<ushort4*>(&xl[p][4 * tid]) = l4;
        }
        if (tid + 256 < 336) {
            ushort4 h4, l4;
            h4.x = f2bf(r1.x); l4.x = f2bf(r1.x - bf2f(h4.x));
            h4.y = f2bf(r1.y); l4.y = f2bf(r1.y - bf2f(h4.y));
            h4.z = f2bf(r1.z); l4.z = f2bf(r1.z - bf2f(h4.z));
            h4.w = f2bf(r1.w); l4.w = f2bf(r1.w - bf2f(h4.w));
            *reinterpret_cast<ushort4*>(&xh[p][4 * (tid + 256)]) = h4;
            *reinterpret_cast<ushort4*>(&xl[p][4 * (tid + 256)]) = l4;
        }
        if (c + 1 < C_IN) {
            const float4* s4 = reinterpret_cast<const float4*>(xbase + (size_t)(c + 1) * L_IN);
            r0 = make_float4(0, 0, 0, 0); r1 = make_float4(0, 0, 0, 0);
            if (tid < v4max) r0 = s4[tid];
            if (tid + 256 < v4max) r1 = s4[tid + 256];
        }
        __syncthreads();

        const ushort* ph = xh[p];
        const ushort* pl = xl[p];
        const uint4* wc = wf4 + (size_t)c * 512 + lane;
#pragma unroll
        for (int s = 0; s < 4; ++s) {
            const int idx = abase + s * 16;    // always even -> 4B aligned
            union { s16x8 v; uint u[4]; } ah, al, bh, bl;
            ah.u[0] = *reinterpret_cast<const uint*>(&ph[idx]);
            ah.u[1] = *reinterpret_cast<const uint*>(&ph[idx + 2]);
            ah.u[2] = *reinterpret_cast<const uint*>(&ph[idx + 4]);
            ah.u[3] = *reinterpret_cast<const uint*>(&ph[idx + 6]);
            al.u[0] = *reinterpret_cast<const uint*>(&pl[idx]);
            al.u[1] = *reinterpret_cast<const uint*>(&pl[idx + 2]);
            al.u[2] = *reinterpret_cast<const uint*>(&pl[idx + 4]);
            al.u[3] = *reinterpret_cast<const uint*>(&pl[idx + 6]);
            uint4 bq = wc[s * 128];
            uint4 lq = wc[s * 128 + 64];
            bh.u[0] = bq.x; bh.u[1] = bq.y; bh.u[2] = bq.z; bh.u[3] = bq.w;
            bl.u[0] = lq.x; bl.u[1] = lq.y; bl.u[2] = lq.z; bl.u[3] = lq.w;
            acc = __builtin_amdgcn_mfma_f32_32x32x16_bf16(ah.v, bh.v, acc, 0, 0, 0);
            acc = __builtin_amdgcn_mfma_f32_32x32x16_bf16(ah.v, bl.v, acc, 0, 0, 0);
            acc = __builtin_amdgcn_mfma_f32_32x32x16_bf16(al.v, bh.v, acc, 0, 0, 0);
        }
    }

    const float bias = c1b[cl];
    float sum = 0.f, sq = 0.f;
    float* yb = y1 + ((size_t)b * C1 + cl) * L1;
#pragma unroll
    for (int q = 0; q < 4; ++q) {
        const int trow = t0 + wv * 32 + 8 * q + 4 * kgrp;
        float4 st;
        st.x = acc[4 * q + 0] + bias;
        st.y = acc[4 * q + 1] + bias;
        st.z = acc[4 * q + 2] + bias;
        st.w = acc[4 * q + 3] + bias;
        if (trow < L1) {
            *reinterpret_cast<float4*>(yb + trow) = st;
            sum += st.x + st.y + st.z + st.w;
            sq  += st.x * st.x + st.y * st.y + st.z * st.z + st.w * st.w;
        }
    }
    sum += __shfl_xor(sum, 32);
    sq  += __shfl_xor(sq, 32);
    if (lane < 32) { redS[wv][cl] = sum; redQ[wv][cl] = sq; }
    __syncthreads();
    if (tid < 64) {
        int o = tid & 31, isQ = tid >> 5;
        float v = isQ ? (redQ[0][o] + redQ[1][o] + redQ[2][o] + redQ[3][o])
                      : (redS[0][o] + redS[1][o] + redS[2][o] + redS[3][o]);
        atomicAdd(&raw1[(isQ ? 1024 : 0) + o * 16], v);
    }
}

// ---------------- conv2 via split-bf16 MFMA (+inline BN1 finalize+apply+relu, BN2 stats) ----------------
// grid B, 192 thr = 3 waves; wave wv owns 32x32 C-tile (t in [wv*32, wv*32+32) x 32 oc).
// x staged packed uint = bf16hi | bf16lo<<16 -> all LDS A-reads are aligned b32, stride-5 conflict-free.
__global__ __launch_bounds__(192) void k_conv2(const float* __restrict__ y1,
                                               const ushort* __restrict__ wfrag2,
                                               const float* __restrict__ c2b,
                                               const float* __restrict__ raw1,
                                               const float* __restrict__ bn1g,
                                               const float* __restrict__ bn1b,
                                               float* __restrict__ y2,
                                               float* __restrict__ raw2) {
    __shared__ uint xs[C1][512];         // 64 KB packed
    __shared__ float fin[64];
    __shared__ float redS[3][32], redQ[3][32];
    const int b = blockIdx.x, tid = threadIdx.x;

    if (tid < 32) {                      // BN1 finalize (redundant per block, cheap)
        const float cnt = 1.f / (float)(B * L1);
        float mean = raw1[tid * 16] * cnt;
        float var = raw1[1024 + tid * 16] * cnt - mean * mean;
        float sc = bn1g[tid] * rsqrtf(var + EPS);
        fin[tid] = sc;
        fin[32 + tid] = bn1b[tid] - mean * sc;
    }
    __syncthreads();

    // stage: y1[b] -> BN+relu -> packed bf16 hi/lo uints, rows padded 496->512 with zeros
    const float4* src = reinterpret_cast<const float4*>(y1 + (size_t)b * (C1 * L1));
    for (int v = tid; v < C1 * 128; v += 192) {
        const int c = v >> 7, i4 = v & 127;
        uint4 o = make_uint4(0, 0, 0, 0);
        if (i4 < 124) {
            const float sc = fin[c], sh = fin[32 + c];
            float4 d = src[c * 124 + i4];
            float e0 = fmaxf(fmaf(d.x, sc, sh), 0.f);
            float e1 = fmaxf(fmaf(d.y, sc, sh), 0.f);
            float e2 = fmaxf(fmaf(d.z, sc, sh), 0.f);
            float e3 = fmaxf(fmaf(d.w, sc, sh), 0.f);
            ushort h0 = f2bf(e0), h1 = f2bf(e1), h2 = f2bf(e2), h3 = f2bf(e3);
            o.x = (uint)h0 | ((uint)f2bf(e0 - bf2f(h0)) << 16);
            o.y = (uint)h1 | ((uint)f2bf(e1 - bf2f(h1)) << 16);
            o.z = (uint)h2 | ((uint)f2bf(e2 - bf2f(h2)) << 16);
            o.w = (uint)h3 | ((uint)f2bf(e3 - bf2f(h3)) << 16);
        }
        *reinterpret_cast<uint4*>(&xs[c][4 * i4]) = o;
    }
    __syncthreads();

    const int lane = tid & 63, wv = tid / 64;
    const int cl = lane & 31;
    const int kgrp = lane >> 5;
    const int tr = wv * 32 + cl;         // A-row (t), up to 95 (row 95 is pad)
    const int tbase = 5 * tr + kgrp * 8;

    f32x16 acc;
#pragma unroll
    for (int i = 0; i < 16; ++i) acc[i] = 0.f;

    const uint4* wf4 = reinterpret_cast<const uint4*>(wfrag2);

    for (int c = 0; c < C1; ++c) {
        const uint* xc = xs[c];
        const uint4* wfc = wf4 + (size_t)c * 256 + lane;
#pragma unroll
        for (int ks = 0; ks < 2; ++ks) {
            const int idx = tbase + ks * 16;
            uint u0 = xc[idx + 0], u1 = xc[idx + 1], u2 = xc[idx + 2], u3 = xc[idx + 3];
            uint u4 = xc[idx + 4], u5 = xc[idx + 5], u6 = xc[idx + 6], u7 = xc[idx + 7];
            union { s16x8 v; uint u[4]; } ah, al, bh, bl;
            ah.u[0] = (u0 & 0xFFFFu) | (u1 << 16);  al.u[0] = (u0 >> 16) | (u1 & 0xFFFF0000u);
            ah.u[1] = (u2 & 0xFFFFu) | (u3 << 16);  al.u[1] = (u2 >> 16) | (u3 & 0xFFFF0000u);
            ah.u[2] = (u4 & 0xFFFFu) | (u5 << 16);  al.u[2] = (u4 >> 16) | (u5 & 0xFFFF0000u);
            ah.u[3] = (u6 & 0xFFFFu) | (u7 << 16);  al.u[3] = (u6 >> 16) | (u7 & 0xFFFF0000u);
            uint4 bq = wfc[ks * 128];
            uint4 lq = wfc[ks * 128 + 64];
            bh.u[0] = bq.x; bh.u[1] = bq.y; bh.u[2] = bq.z; bh.u[3] = bq.w;
            bl.u[0] = lq.x; bl.u[1] = lq.y; bl.u[2] = lq.z; bl.u[3] = lq.w;
            acc = __builtin_amdgcn_mfma_f32_32x32x16_bf16(ah.v, bh.v, acc, 0, 0, 0);
            acc = __builtin_amdgcn_mfma_f32_32x32x16_bf16(ah.v, bl.v, acc, 0, 0, 0);
            acc = __builtin_amdgcn_mfma_f32_32x32x16_bf16(al.v, bh.v, acc, 0, 0, 0);
        }
    }

    // epilogue: bias, scattered-coalesced stores to y2[b][t][oc], BN2 stats
    const float bias = c2b[cl];
    float sum = 0.f, sq = 0.f;
#pragma unroll
    for (int q = 0; q < 4; ++q) {
#pragma unroll
        for (int j = 0; j < 4; ++j) {
            const int t = wv * 32 + 8 * q + 4 * kgrp + j;
            const float v = acc[4 * q + j] + bias;
            if (t < L2) {
                y2[((size_t)b * L2 + t) * NF + cl] = v;
                sum += v; sq += v * v;
            }
        }
    }
    sum += __shfl_xor(sum, 32);
    sq  += __shfl_xor(sq, 32);
    if (lane < 32) { redS[wv][cl] = sum; redQ[wv][cl] = sq; }
    __syncthreads();
    if (tid < 64) {
        int o = tid & 31, isQ = tid >> 5;
        float v = isQ ? (redQ[0][o] + redQ[1][o] + redQ[2][o])
                      : (redS[0][o] + redS[1][o] + redS[2][o]);
        atomicAdd(&raw2[(isQ ? 1024 : 0) + o * 16], v);
    }
}

// ---------------- BN2 finalize (inline) + relu, input proj, LN1, fold Wh ----------------
// grid exactly 190 blocks x 256 (= B*T threads). xt2 layout [T][B][HID].
__global__ __launch_bounds__(256) void k_proj(const float* __restrict__ y2,
                                              const float* __restrict__ raw2,
                                              const float* __restrict__ bn2g,
                                              const float* __restrict__ bn2b,
                                              const float* __restrict__ Wi,
                                              const float* __restrict__ bi,
                                              const float* __restrict__ ln1g,
                                              const float* __restrict__ ln1b,
                                              const float* __restrict__ Wh,
                                              const float* __restrict__ bh,
                                              float* __restrict__ xt2) {
    __shared__ float fin[64];
    if (threadIdx.x < 32) {
        const float cnt = 1.f / (float)(B * L2);
        float mean = raw2[threadIdx.x * 16] * cnt;
        float var = raw2[1024 + threadIdx.x * 16] * cnt - mean * mean;
        float sc = bn2g[threadIdx.x] * rsqrtf(var + EPS);
        fin[threadIdx.x] = sc;
        fin[32 + threadIdx.x] = bn2b[threadIdx.x] - mean * sc;
    }
    __syncthreads();

    const int r = blockIdx.x * 256 + threadIdx.x;
    const int b = r / 95, t = r - b * 95;

    const float4* row = reinterpret_cast<const float4*>(y2 + (size_t)r * NF);
    float u[NF];
#pragma unroll
    for (int f4 = 0; f4 < 8; ++f4) {
        float4 v = row[f4];
        u[4*f4]   = fmaxf(fmaf(v.x, fin[4*f4],   fin[32 + 4*f4]),   0.f);
        u[4*f4+1] = fmaxf(fmaf(v.y, fin[4*f4+1], fin[32 + 4*f4+1]), 0.f);
        u[4*f4+2] = fmaxf(fmaf(v.z, fin[4*f4+2], fin[32 + 4*f4+2]), 0.f);
        u[4*f4+3] = fmaxf(fmaf(v.w, fin[4*f4+3], fin[32 + 4*f4+3]), 0.f);
    }
    float xln[LAT];
    float s = 0.f, q = 0.f;
#pragma unroll
    for (int l = 0; l < LAT; ++l) {
        float a = bi[l];
#pragma unroll
        for (int f = 0; f < NF; ++f) a = fmaf(u[f], Wi[l * NF + f], a);
        xln[l] = a; s += a; q += a * a;
    }
    const float m = s * (1.f / LAT);
    const float inv = rsqrtf(q * (1.f / LAT) - m * m + EPS);
#pragma unroll
    for (int l = 0; l < LAT; ++l) xln[l] = (xln[l] - m) * inv * ln1g[l] + ln1b[l];

    float4* dst = reinterpret_cast<float4*>(xt2 + ((size_t)t * B + b) * HID);
#pragma unroll
    for (int j4 = 0; j4 < 16; ++j4) {
        float4 o4;
        float a0 = bh[4*j4], a1 = bh[4*j4+1], a2 = bh[4*j4+2], a3 = bh[4*j4+3];
#pragma unroll
        for (int l = 0; l < LAT; ++l) {
            float xl = xln[l];
            a0 = fmaf(xl, Wh[(4*j4)   * LAT + l], a0);
            a1 = fmaf(xl, Wh[(4*j4+1) * LAT + l], a1);
            a2 = fmaf(xl, Wh[(4*j4+2) * LAT + l], a2);
            a3 = fmaf(xl, Wh[(4*j4+3) * LAT + l], a3);
        }
        o4.x = a0; o4.y = a1; o4.z = a2; o4.w = a3;
        dst[j4] = o4;
    }
}

// ---------------- RNN scan + pooled mean + final linear ----------------
// 1 wave per batch row. LN2 folded into Wr-dot: a2 = inv*(dot_wg(a) - m*S1) + S2,
// so the LDS broadcast+dot overlaps the shfl reduce. Multi-accumulator dots.
__global__ __launch_bounds__(64) void k_rnn(const float* __restrict__ xt2,
                                            const float* __restrict__ Wh,
                                            const float* __restrict__ ln2g,
                                            const float* __restrict__ ln2b,
                                            const float* __restrict__ Wr,
                                            const float* __restrict__ br,
                                            const float* __restrict__ Wo,
                                            const float* __restrict__ bo,
                                            float* __restrict__ out) {
    __shared__ __align__(16) float aS[64];
    __shared__ __align__(16) float hS[32];
    const int lane = threadIdx.x;
    const int b = blockIdx.x;
    const int l = lane & 31;

    float whv[LAT];
#pragma unroll
    for (int i = 0; i < LAT; ++i) whv[i] = Wh[lane * LAT + i];

    // wg[j] = Wr[l][j]*g[j]; S1 = sum wg; S2 = sum Wr[l][j]*b[j] + br[l]
    float wg[HID];
    float S1 = 0.f, S2 = br[l];
#pragma unroll
    for (int j = 0; j < HID; ++j) {
        float w = Wr[l * HID + j];
        wg[j] = w * ln2g[j];
        S1 += wg[j];
        S2 = fmaf(w, ln2b[j], S2);
    }

    float hfull[LAT];
#pragma unroll
    for (int i = 0; i < LAT; ++i) hfull[i] = 0.f;
    float pooled = 0.f;
    float xq = xt2[(size_t)b * HID + lane];

    for (int t = 0; t < T; ++t) {
        float xq_next = 0.f;
        if (t + 1 < T) xq_next = xt2[((size_t)(t + 1) * B + b) * HID + lane];

        // a = relu(xq + Wh[lane]·hfull)  -- 4 accumulators
        float a0 = xq, a1 = 0.f, a2c = 0.f, a3c = 0.f;
#pragma unroll
        for (int i = 0; i < 8; ++i) {
            a0  = fmaf(hfull[4*i+0], whv[4*i+0], a0);
            a1  = fmaf(hfull[4*i+1], whv[4*i+1], a1);
            a2c = fmaf(hfull[4*i+2], whv[4*i+2], a2c);
            a3c = fmaf(hfull[4*i+3], whv[4*i+3], a3c);
        }
        const float a = fmaxf((a0 + a1) + (a2c + a3c), 0.f);

        aS[lane] = a;
        asm volatile("s_waitcnt lgkmcnt(0)" ::: "memory");

        // broadcast dot (overlaps shfl reduce below)
        float d0 = 0.f, d1 = 0.f, d2 = 0.f, d3 = 0.f;
#pragma unroll
        for (int i = 0; i < 16; ++i) {
            float4 v = reinterpret_cast<const float4*>(aS)[i];
            d0 = fmaf(v.x, wg[4*i+0], d0); d1 = fmaf(v.y, wg[4*i+1], d1);
            d2 = fmaf(v.z, wg[4*i+2], d2); d3 = fmaf(v.w, wg[4*i+3], d3);
        }
        float s = a, q = a * a;
#pragma unroll
        for (int off = 32; off >= 1; off >>= 1) { s += __shfl_xor(s, off); q += __shfl_xor(q, off); }
        const float m = s * (1.f / HID);
        const float inv = __builtin_amdgcn_rsqf(q * (1.f / HID) - m * m + EPS);
        const float dot = (d0 + d1) + (d2 + d3);
        const float a2v = fmaf(inv, dot - m * S1, S2);

        const float z = __builtin_amdgcn_exp2f(2.8853900817779268f * a2v);
        const float h = 1.f - 2.f * __builtin_amdgcn_rcpf(z + 1.f);
        pooled += h;

        if (lane < 32) hS[lane] = h;
        asm volatile("s_waitcnt lgkmcnt(0)" ::: "memory");
#pragma unroll
        for (int i = 0; i < 8; ++i) {
            float4 hv = reinterpret_cast<const float4*>(hS)[i];
            hfull[4*i] = hv.x; hfull[4*i+1] = hv.y; hfull[4*i+2] = hv.z; hfull[4*i+3] = hv.w;
        }
        xq = xq_next;
    }
    pooled *= (1.f / T);
    if (lane < 32) aS[lane] = pooled;
    asm volatile("s_waitcnt lgkmcnt(0)" ::: "memory");

    float wov[LAT];
#pragma unroll
    for (int i = 0; i < LAT; ++i) wov[i] = Wo[l * LAT + i];
    float b0 = bo[l], b1 = 0.f, b2 = 0.f, b3 = 0.f;
#pragma unroll
    for (int i = 0; i < 8; ++i) {
        float4 pv = reinterpret_cast<const float4*>(aS)[i];
        b0 = fmaf(pv.x, wov[4*i+0], b0); b1 = fmaf(pv.y, wov[4*i+1], b1);
        b2 = fmaf(pv.z, wov[4*i+2], b2); b3 = fmaf(pv.w, wov[4*i+3], b3);
    }
    if (lane < 32) out[(size_t)b * LAT + l] = (b0 + b1) + (b2 + b3);
}

extern "C" void kernel_launch(void* const* d_in, const int* in_sizes, int n_in,
                              void* d_out, int out_size, void* d_ws, size_t ws_size,
                              hipStream_t stream) {
    const float* x    = (const float*)d_in[0];
    const float* c1w  = (const float*)d_in[1];
    const float* c1b  = (const float*)d_in[2];
    const float* bn1g = (const float*)d_in[3];
    const float* bn1b = (const float*)d_in[4];
    const float* c2w  = (const float*)d_in[5];
    const float* c2b  = (const float*)d_in[6];
    const float* bn2g = (const float*)d_in[7];
    const float* bn2b = (const float*)d_in[8];
    const float* Wi   = (const float*)d_in[9];
    const float* bi   = (const float*)d_in[10];
    const float* ln1g = (const float*)d_in[11];
    const float* ln1b = (const float*)d_in[12];
    const float* Wh   = (const float*)d_in[13];
    const float* bh   = (const float*)d_in[14];
    const float* ln2g = (const float*)d_in[15];
    const float* ln2b = (const float*)d_in[16];
    const float* Wr   = (const float*)d_in[17];
    const float* br   = (const float*)d_in[18];
    const float* Wo   = (const float*)d_in[19];
    const float* bo   = (const float*)d_in[20];

    float* ws = (float*)d_ws;
    float* raw1 = ws;                      // 2048 (S at o*16, Q at 1024+o*16)
    float* raw2 = ws + 2048;               // 2048
    ushort* wfrag1 = (ushort*)(ws + 4096); // 49152 ushorts = 24576 floats -> ends 28672
    ushort* wfrag2 = (ushort*)(ws + 28672);// 65536 ushorts = 32768 floats -> ends 61440
    float* y1   = ws + 61440;              // 8126464 -> ends 8187904
    float* y2   = ws + 8187904;            // 1556480 -> ends 9744384
    float* xt2  = y1;                      // alias y1 (dead after conv2)
    float* out  = (float*)d_out;

    hipMemsetAsync(raw1, 0, 4096 * sizeof(float), stream);
    k_prep_w<<<56, 256, 0, stream>>>(c1w, c2w, wfrag1, wfrag2);
    k_conv1<<<dim3(4, B), 256, 0, stream>>>(x, wfrag1, c1b, y1, raw1);
    k_conv2<<<B, 192, 0, stream>>>(y1, wfrag2, c2b, raw1, bn1g, bn1b, y2, raw2);
    k_proj<<<190, 256, 0, stream>>>(y2, raw2, bn2g, bn2b, Wi, bi, ln1g, ln1b, Wh, bh, xt2);
    k_rnn<<<B, 64, 0, stream>>>(xt2, Wh, ln2g, ln2b, Wr, br, Wo, bo, out);
}